// Round 1
// baseline (414.165 us; speedup 1.0000x reference)
//
#include <hip/hip_runtime.h>
#include <hip/hip_bf16.h>
#include <math.h>

typedef __bf16 bf16_t;
typedef __bf16 bf16x8 __attribute__((ext_vector_type(8)));
typedef __bf16 bf16x4 __attribute__((ext_vector_type(4)));
typedef float f32x4 __attribute__((ext_vector_type(4)));

#define DM 1024
#define SEQL 2048
#define NTOK 4096

__device__ __forceinline__ bf16x8 cvt8(float4 a, float4 b){
  bf16x8 r;
  r[0]=(__bf16)a.x; r[1]=(__bf16)a.y; r[2]=(__bf16)a.z; r[3]=(__bf16)a.w;
  r[4]=(__bf16)b.x; r[5]=(__bf16)b.y; r[6]=(__bf16)b.z; r[7]=(__bf16)b.w;
  return r;
}

// ---------------- LayerNorm: one block (256 thr) per row of 1024 ----------------
__global__ __launch_bounds__(256) void ln_kernel(const float* __restrict__ in,
    const float* __restrict__ g, const float* __restrict__ bta,
    bf16_t* __restrict__ outp)
{
  const int row = blockIdx.x;
  const int t = threadIdx.x;
  const float4 v = *(const float4*)(in + (size_t)row*DM + t*4);
  float s  = v.x+v.y+v.z+v.w;
  float sq = v.x*v.x+v.y*v.y+v.z*v.z+v.w*v.w;
  #pragma unroll
  for (int m=1;m<64;m<<=1){ s += __shfl_xor(s,m); sq += __shfl_xor(sq,m); }
  __shared__ float red[8];
  const int w = t>>6;
  if ((t&63)==0){ red[w]=s; red[4+w]=sq; }
  __syncthreads();
  s  = red[0]+red[1]+red[2]+red[3];
  sq = red[4]+red[5]+red[6]+red[7];
  const float mean = s*(1.f/DM);
  const float var  = sq*(1.f/DM) - mean*mean;
  const float rstd = rsqrtf(var + 1e-5f);
  const float4 gg = *(const float4*)(g + t*4);
  const float4 bb = *(const float4*)(bta + t*4);
  bf16x4 o;
  o[0]=(__bf16)((v.x-mean)*rstd*gg.x+bb.x);
  o[1]=(__bf16)((v.y-mean)*rstd*gg.y+bb.y);
  o[2]=(__bf16)((v.z-mean)*rstd*gg.z+bb.z);
  o[3]=(__bf16)((v.w-mean)*rstd*gg.w+bb.w);
  *(bf16x4*)(outp + (size_t)row*DM + t*4) = o;
}

// ---------------- GEMM: C[M,N] = A[M,K](bf16) x Bw[N,K](fp32)^T ----------------
// EPI: 0 = store bf16; 1 = store fp32 (X + C); 2 = store bf16 gelu(C)
template<int EPI>
__global__ __launch_bounds__(256) void gemm_bt(
    const bf16_t* __restrict__ A, const float* __restrict__ Bw,
    void* __restrict__ Cout, const float* __restrict__ X,
    int N, int K)
{
  constexpr int BM=128, BN=128, BK=32;
  __shared__ __align__(16) bf16_t As[BM][BK+8];
  __shared__ __align__(16) bf16_t Bs[BN][BK+8];
  const int tid  = threadIdx.x;
  const int lane = tid & 63;
  const int wid  = tid >> 6;
  const int wr = (wid>>1)*64, wc = (wid&1)*64;
  const int bm = blockIdx.x*BM, bn = blockIdx.y*BN;
  const int row0 = tid>>2, row1 = row0+64;
  const int kcol = (tid&3)*8;

  const bf16_t* Ap0 = A  + (size_t)(bm+row0)*K + kcol;
  const bf16_t* Ap1 = A  + (size_t)(bm+row1)*K + kcol;
  const float*  Bp0 = Bw + (size_t)(bn+row0)*K + kcol;
  const float*  Bp1 = Bw + (size_t)(bn+row1)*K + kcol;

  f32x4 acc[4][4] = {};

  float4 ra0, ra1, rb0, rb1, rb2, rb3;
  ra0 = *(const float4*)Ap0;      ra1 = *(const float4*)Ap1;
  rb0 = *(const float4*)Bp0;      rb1 = *(const float4*)(Bp0+4);
  rb2 = *(const float4*)Bp1;      rb3 = *(const float4*)(Bp1+4);

  for (int k0 = 0; k0 < K; k0 += BK){
    __syncthreads();
    *(float4*)&As[row0][kcol] = ra0;
    *(float4*)&As[row1][kcol] = ra1;
    *(bf16x8*)&Bs[row0][kcol] = cvt8(rb0, rb1);
    *(bf16x8*)&Bs[row1][kcol] = cvt8(rb2, rb3);
    __syncthreads();
    if (k0 + BK < K){
      ra0 = *(const float4*)(Ap0 + k0 + BK);
      ra1 = *(const float4*)(Ap1 + k0 + BK);
      rb0 = *(const float4*)(Bp0 + k0 + BK);
      rb1 = *(const float4*)(Bp0 + k0 + BK + 4);
      rb2 = *(const float4*)(Bp1 + k0 + BK);
      rb3 = *(const float4*)(Bp1 + k0 + BK + 4);
    }
    bf16x8 af[4], bfv[4];
    #pragma unroll
    for (int fm=0; fm<4; fm++)
      af[fm] = *(const bf16x8*)&As[wr + fm*16 + (lane&15)][(lane>>4)*8];
    #pragma unroll
    for (int fn=0; fn<4; fn++)
      bfv[fn] = *(const bf16x8*)&Bs[wc + fn*16 + (lane&15)][(lane>>4)*8];
    #pragma unroll
    for (int fm=0; fm<4; fm++)
      #pragma unroll
      for (int fn=0; fn<4; fn++)
        acc[fm][fn] = __builtin_amdgcn_mfma_f32_16x16x32_bf16(af[fm], bfv[fn], acc[fm][fn], 0, 0, 0);
  }

  #pragma unroll
  for (int fm=0; fm<4; fm++)
    #pragma unroll
    for (int fn=0; fn<4; fn++)
      #pragma unroll
      for (int i=0; i<4; i++){
        const int r = bm + wr + fm*16 + (lane>>4)*4 + i;
        const int c = bn + wc + fn*16 + (lane&15);
        const size_t idx = (size_t)r*N + c;
        const float vv = acc[fm][fn][i];
        if constexpr (EPI==0){
          ((bf16_t*)Cout)[idx] = (__bf16)vv;
        } else if constexpr (EPI==1){
          ((float*)Cout)[idx] = X[idx] + vv;
        } else {
          const float ge = 0.5f*vv*(1.0f + erff(vv*0.70710678118654752f));
          ((bf16_t*)Cout)[idx] = (__bf16)ge;
        }
      }
}

// ---------------- Flash attention: block = 128 q-rows of one (b,h); 4 waves x 32 rows ----------------
__global__ __launch_bounds__(256) void attn_kernel(
    const bf16_t* __restrict__ Qm, const bf16_t* __restrict__ Km,
    const bf16_t* __restrict__ Vm, bf16_t* __restrict__ Ctx)
{
  __shared__ __align__(16) bf16_t Ks[64][72];
  __shared__ __align__(16) bf16_t Vt[64][72];   // V transposed: [e][k], k XOR-swizzled
  __shared__ __align__(16) bf16_t Ps[4][32][72];
  const int tid = threadIdx.x, lane = tid & 63, w = tid >> 6;
  const int bh = blockIdx.y, b = bh >> 4, h = bh & 15;
  const int qbase = blockIdx.x*128 + w*32;
  const size_t tok0 = (size_t)b * SEQL;
  const int ch0 = h*64;

  // Q fragments held in registers for the whole kernel
  bf16x8 aq[2][2];
  #pragma unroll
  for (int fm=0; fm<2; fm++)
    #pragma unroll
    for (int ks=0; ks<2; ks++)
      aq[fm][ks] = *(const bf16x8*)(Qm + (tok0 + qbase + fm*16 + (lane&15))*DM + ch0 + ks*32 + (lane>>4)*8);

  float mrun[2][4], lrun[2][4];
  f32x4 o[2][4] = {};
  #pragma unroll
  for (int fm=0; fm<2; fm++)
    #pragma unroll
    for (int i=0;i<4;i++){ mrun[fm][i] = -1e30f; lrun[fm][i] = 0.f; }

  const int sr = tid>>3;        // 0..31
  const int sc = (tid&7)*8;     // 0..56

  for (int kt=0; kt<SEQL/64; kt++){
    // ---- stage K tile and transposed V tile ----
    #pragma unroll
    for (int it=0; it<2; it++){
      const int r = sr + it*32;
      const size_t grow = (tok0 + (size_t)kt*64 + r)*DM + ch0 + sc;
      float4 kv = *(const float4*)(Km + grow);
      *(float4*)&Ks[r][sc] = kv;
      float4 vv = *(const float4*)(Vm + grow);
      const bf16_t* ve = (const bf16_t*)&vv;
      #pragma unroll
      for (int j=0;j<8;j++){
        const int e = sc + j;
        const int swz = (e>>3)&7;
        Vt[e][r ^ (swz<<3)] = ve[j];
      }
    }
    __syncthreads();

    // ---- S = Q K^T (scaled) ----
    f32x4 s[2][4] = {};
    #pragma unroll
    for (int ks=0; ks<2; ks++){
      bf16x8 bk[4];
      #pragma unroll
      for (int fn=0; fn<4; fn++)
        bk[fn] = *(const bf16x8*)&Ks[fn*16 + (lane&15)][ks*32 + (lane>>4)*8];
      #pragma unroll
      for (int fm=0; fm<2; fm++)
        #pragma unroll
        for (int fn=0; fn<4; fn++)
          s[fm][fn] = __builtin_amdgcn_mfma_f32_16x16x32_bf16(aq[fm][ks], bk[fn], s[fm][fn], 0, 0, 0);
    }

    // ---- online softmax (C-layout rows; row-reduce over 16-lane group) ----
    #pragma unroll
    for (int fm=0; fm<2; fm++)
      #pragma unroll
      for (int i=0; i<4; i++){
        float mx = fmaxf(fmaxf(s[fm][0][i]*0.125f, s[fm][1][i]*0.125f),
                         fmaxf(s[fm][2][i]*0.125f, s[fm][3][i]*0.125f));
        #pragma unroll
        for (int m=1; m<16; m<<=1) mx = fmaxf(mx, __shfl_xor(mx, m));
        const float mnew = fmaxf(mrun[fm][i], mx);
        const float alpha = __expf(mrun[fm][i] - mnew);
        mrun[fm][i] = mnew;
        float rs = 0.f;
        #pragma unroll
        for (int fn=0; fn<4; fn++){
          const float p = __expf(s[fm][fn][i]*0.125f - mnew);
          s[fm][fn][i] = p;
          rs += p;
        }
        #pragma unroll
        for (int m=1; m<16; m<<=1) rs += __shfl_xor(rs, m);
        lrun[fm][i] = lrun[fm][i]*alpha + rs;
        #pragma unroll
        for (int ne=0; ne<4; ne++) o[fm][ne][i] *= alpha;
      }

    // ---- P -> per-wave LDS (C-layout scatter), reload as A-fragments ----
    #pragma unroll
    for (int fm=0; fm<2; fm++)
      #pragma unroll
      for (int fn=0; fn<4; fn++)
        #pragma unroll
        for (int i=0; i<4; i++)
          Ps[w][fm*16 + (lane>>4)*4 + i][fn*16 + (lane&15)] = (__bf16)s[fm][fn][i];

    // ---- O += P V ----
    #pragma unroll
    for (int ks=0; ks<2; ks++){
      bf16x8 pa[2], bv[4];
      #pragma unroll
      for (int fm=0; fm<2; fm++)
        pa[fm] = *(const bf16x8*)&Ps[w][fm*16 + (lane&15)][ks*32 + (lane>>4)*8];
      #pragma unroll
      for (int ne=0; ne<4; ne++){
        const int e = ne*16 + (lane&15);
        const int ue = (e>>3)&7;
        const int t8 = ks*4 + (lane>>4);
        bv[ne] = *(const bf16x8*)&Vt[e][(t8 ^ ue)<<3];
      }
      #pragma unroll
      for (int fm=0; fm<2; fm++)
        #pragma unroll
        for (int ne=0; ne<4; ne++)
          o[fm][ne] = __builtin_amdgcn_mfma_f32_16x16x32_bf16(pa[fm], bv[ne], o[fm][ne], 0, 0, 0);
    }
    __syncthreads();
  }

  // ---- epilogue: O / l, store bf16 ctx in [token][h*64+e] layout ----
  #pragma unroll
  for (int fm=0; fm<2; fm++)
    #pragma unroll
    for (int ne=0; ne<4; ne++)
      #pragma unroll
      for (int i=0; i<4; i++){
        const int r = qbase + fm*16 + (lane>>4)*4 + i;
        const float val = o[fm][ne][i] / lrun[fm][i];
        Ctx[(tok0 + r)*DM + ch0 + ne*16 + (lane&15)] = (__bf16)val;
      }
}

// ---------------- launcher ----------------
extern "C" void kernel_launch(void* const* d_in, const int* in_sizes, int n_in,
                              void* d_out, int out_size, void* d_ws, size_t ws_size,
                              hipStream_t stream)
{
  (void)in_sizes; (void)n_in; (void)out_size; (void)ws_size;
  const float* x  = (const float*)d_in[0];
  const float* wq = (const float*)d_in[1];
  const float* wk = (const float*)d_in[2];
  const float* wv = (const float*)d_in[3];
  const float* wo = (const float*)d_in[4];
  const float* w1 = (const float*)d_in[5];
  const float* w2 = (const float*)d_in[6];
  const float* g1 = (const float*)d_in[7];
  const float* b1 = (const float*)d_in[8];
  const float* g2 = (const float*)d_in[9];
  const float* b2 = (const float*)d_in[10];
  float* out = (float*)d_out;
  char* ws = (char*)d_ws;
  const size_t MB = 1024ull*1024ull;

  bf16_t* h1  = (bf16_t*)(ws);            // 8MB
  bf16_t* q   = (bf16_t*)(ws + 8*MB);     // 8MB
  bf16_t* k   = (bf16_t*)(ws + 16*MB);    // 8MB
  bf16_t* v   = (bf16_t*)(ws + 24*MB);    // 8MB
  bf16_t* ffm = (bf16_t*)(ws);            // 32MB, aliases h1/q/k/v (dead by then)
  bf16_t* ctx = (bf16_t*)(ws + 32*MB);    // 8MB
  bf16_t* h2  = ctx;                      // aliases ctx (dead by then)
  float*  res2= (float*)(ws + 40*MB);     // 16MB

  ln_kernel<<<NTOK, 256, 0, stream>>>(x, g1, b1, h1);
  gemm_bt<0><<<dim3(32, 8), 256, 0, stream>>>(h1, wq, (void*)q, nullptr, 1024, 1024);
  gemm_bt<0><<<dim3(32, 8), 256, 0, stream>>>(h1, wk, (void*)k, nullptr, 1024, 1024);
  gemm_bt<0><<<dim3(32, 8), 256, 0, stream>>>(h1, wv, (void*)v, nullptr, 1024, 1024);
  attn_kernel<<<dim3(16, 32), 256, 0, stream>>>(q, k, v, ctx);
  gemm_bt<1><<<dim3(32, 8), 256, 0, stream>>>(ctx, wo, (void*)res2, x, 1024, 1024);
  ln_kernel<<<NTOK, 256, 0, stream>>>(res2, g2, b2, h2);
  gemm_bt<2><<<dim3(32, 32), 256, 0, stream>>>(h2, w1, (void*)ffm, nullptr, 4096, 1024);
  gemm_bt<1><<<dim3(32, 8), 256, 0, stream>>>(ffm, w2, (void*)out, x, 1024, 4096);
}

// Round 2
// 310.426 us; speedup vs baseline: 1.3342x; 1.3342x over previous
//
#include <hip/hip_runtime.h>
#include <hip/hip_bf16.h>
#include <math.h>

typedef __bf16 bf16_t;
typedef __bf16 bf16x8 __attribute__((ext_vector_type(8)));
typedef __bf16 bf16x4 __attribute__((ext_vector_type(4)));
typedef float f32x4 __attribute__((ext_vector_type(4)));
typedef unsigned int u32;
typedef u32 u32x2 __attribute__((ext_vector_type(2)));

#define DM 1024
#define SEQL 2048
#define NTOK 4096
#define QKVN 3072

__device__ __forceinline__ void gload_lds16(const bf16_t* g, bf16_t* l){
  __builtin_amdgcn_global_load_lds((const __attribute__((address_space(1))) void*)g,
                                   (__attribute__((address_space(3))) void*)l, 16, 0, 0);
}
__device__ __forceinline__ u32 ldsoff(const void* p){
  return (u32)(size_t)(__attribute__((address_space(3))) const void*)p;
}
__device__ __forceinline__ u32x2 tr64(u32 byte_off){
  u32x2 d;
  asm volatile("ds_read_b64_tr_b16 %0, %1" : "=v"(d) : "v"(byte_off));
  return d;
}

// ---------------- f32 -> bf16 convert (weights) ----------------
__global__ __launch_bounds__(256) void cvt_kernel(const float* __restrict__ src,
    bf16_t* __restrict__ dst, int n)
{
  const int i = (blockIdx.x*256 + threadIdx.x)*4;
  if (i < n){
    const float4 v = *(const float4*)(src + i);
    bf16x4 o; o[0]=(__bf16)v.x; o[1]=(__bf16)v.y; o[2]=(__bf16)v.z; o[3]=(__bf16)v.w;
    *(bf16x4*)(dst + i) = o;
  }
}

// ---------------- LayerNorm: one block (256 thr) per row of 1024 ----------------
__global__ __launch_bounds__(256) void ln_kernel(const float* __restrict__ in,
    const float* __restrict__ g, const float* __restrict__ bta,
    bf16_t* __restrict__ outp)
{
  const int row = blockIdx.x;
  const int t = threadIdx.x;
  const float4 v = *(const float4*)(in + (size_t)row*DM + t*4);
  float s  = v.x+v.y+v.z+v.w;
  float sq = v.x*v.x+v.y*v.y+v.z*v.z+v.w*v.w;
  #pragma unroll
  for (int m=1;m<64;m<<=1){ s += __shfl_xor(s,m); sq += __shfl_xor(sq,m); }
  __shared__ float red[8];
  const int w = t>>6;
  if ((t&63)==0){ red[w]=s; red[4+w]=sq; }
  __syncthreads();
  s  = red[0]+red[1]+red[2]+red[3];
  sq = red[4]+red[5]+red[6]+red[7];
  const float mean = s*(1.f/DM);
  const float var  = sq*(1.f/DM) - mean*mean;
  const float rstd = rsqrtf(var + 1e-5f);
  const float4 gg = *(const float4*)(g + t*4);
  const float4 bb = *(const float4*)(bta + t*4);
  bf16x4 o;
  o[0]=(__bf16)((v.x-mean)*rstd*gg.x+bb.x);
  o[1]=(__bf16)((v.y-mean)*rstd*gg.y+bb.y);
  o[2]=(__bf16)((v.z-mean)*rstd*gg.z+bb.z);
  o[3]=(__bf16)((v.w-mean)*rstd*gg.w+bb.w);
  *(bf16x4*)(outp + (size_t)row*DM + t*4) = o;
}

// ---------------- GEMM: C[M,N] = A[M,K](bf16) x Bw[N,K](bf16)^T ----------------
// EPI: 0 = store bf16; 1 = store fp32 (X + C); 2 = store bf16 gelu(C)
// m97 structure: global_load_lds w16, double-buffered LDS, 1 barrier/tile.
template<int EPI, int BM>
__global__ __launch_bounds__(256) void gemm_bt(
    const bf16_t* __restrict__ A, const bf16_t* __restrict__ Bw,
    void* __restrict__ Cout, const float* __restrict__ X,
    int N, int K)
{
  constexpr int BN=128, BK=32;
  constexpr int FM = BM/32;           // 128 -> 4, 64 -> 2 row-frags per wave
  __shared__ __align__(16) bf16_t As[2][BM][BK];
  __shared__ __align__(16) bf16_t Bs[2][BN][BK];
  const int tid = threadIdx.x, lane = tid&63, wid = tid>>6;
  const int bm = blockIdx.x*BM, bn = blockIdx.y*BN;
  const int wr = (wid>>1)*(BM/2), wc = (wid&1)*64;
  const int grow = lane>>2, gk = (lane&3)*8;

  f32x4 acc[FM][4] = {};

  const int NT = K/BK;
  // stage tile t into buf
  auto stage = [&](int buf, int k0){
    #pragma unroll
    for (int c = wid; c < BM/16; c += 4)
      gload_lds16(A + (size_t)(bm + c*16 + grow)*K + k0 + gk, &As[buf][c*16][0]);
    #pragma unroll
    for (int c = wid; c < 8; c += 4)
      gload_lds16(Bw + (size_t)(bn + c*16 + grow)*K + k0 + gk, &Bs[buf][c*16][0]);
  };

  stage(0, 0);
  for (int t=0; t<NT; t++){
    __syncthreads();                       // drains vmcnt: staged tile t ready
    if (t+1 < NT) stage((t+1)&1, (t+1)*BK);
    const int b = t&1;
    bf16x8 af[FM], bfv[4];
    #pragma unroll
    for (int fm=0; fm<FM; fm++)
      af[fm] = *(const bf16x8*)&As[b][wr+fm*16+(lane&15)][(lane>>4)*8];
    #pragma unroll
    for (int fn=0; fn<4; fn++)
      bfv[fn] = *(const bf16x8*)&Bs[b][wc+fn*16+(lane&15)][(lane>>4)*8];
    #pragma unroll
    for (int fm=0; fm<FM; fm++)
      #pragma unroll
      for (int fn=0; fn<4; fn++)
        acc[fm][fn] = __builtin_amdgcn_mfma_f32_16x16x32_bf16(af[fm], bfv[fn], acc[fm][fn], 0, 0, 0);
  }

  #pragma unroll
  for (int fm=0; fm<FM; fm++)
    #pragma unroll
    for (int fn=0; fn<4; fn++)
      #pragma unroll
      for (int i=0; i<4; i++){
        const int r = bm + wr + fm*16 + (lane>>4)*4 + i;
        const int c = bn + wc + fn*16 + (lane&15);
        const size_t idx = (size_t)r*N + c;
        const float vv = acc[fm][fn][i];
        if constexpr (EPI==0){
          ((bf16_t*)Cout)[idx] = (__bf16)vv;
        } else if constexpr (EPI==1){
          ((float*)Cout)[idx] = X[idx] + vv;
        } else {
          const float ge = 0.5f*vv*(1.0f + erff(vv*0.70710678118654752f));
          ((bf16_t*)Cout)[idx] = (__bf16)ge;
        }
      }
}

// ---------------- Flash attention: 512 thr, 8 waves x 16 q-rows = 128 q-rows/block ----------
// K: [64][64] XOR-swizzled rows; V: [k/4][e/16][4][16] subtiled (pad 72) for tr-reads;
// P: per-wave k-major subtiled (pad 72) for tr-reads. Double-buffered K/V, 1 barrier/iter.
__global__ __launch_bounds__(512, 4) void attn_kernel(
    const bf16_t* __restrict__ QKV, bf16_t* __restrict__ Ctx)
{
  __shared__ __align__(16) bf16_t Ks[2][64*64];
  __shared__ __align__(16) bf16_t Vs[2][16*4*72];
  __shared__ __align__(16) bf16_t PT[8][16*72];
  const int tid = threadIdx.x, lane = tid&63, w = tid>>6;
  const int g = lane>>4, q16 = lane&15;
  const int bh = blockIdx.y, b = bh>>4, h = bh&15;
  const int qr0 = blockIdx.x*128 + w*16;
  const size_t tok0 = (size_t)b*SEQL;
  const int ch0 = h*64;

  // Q fragments, pre-scaled by 1/sqrt(64)=0.125 (exact in bf16)
  bf16x8 aq[2];
  #pragma unroll
  for (int ks=0; ks<2; ks++){
    bf16x8 t = *(const bf16x8*)(QKV + (tok0+qr0+q16)*QKVN + ch0 + ks*32 + g*8);
    #pragma unroll
    for (int j=0;j<8;j++) t[j] = (__bf16)((float)t[j]*0.125f);
    aq[ks] = t;
  }

  // staging geometry: 512 threads cover 64 rows x 8 chunks of 8 elems
  const int srow = tid>>3, sc8 = (tid&7)*8;
  const bf16_t* kptr = QKV + (tok0+srow)*QKVN + 1024 + ch0 + sc8;
  const bf16_t* vptr = kptr + 1024;
  const int kwoff = srow*64 + (sc8 ^ ((srow&7)<<3));                       // elems
  const int vwoff = ((srow>>2)*4 + (sc8>>4))*72 + (srow&3)*16 + (sc8&15);  // elems

  const u32 pt0 = ldsoff(&PT[w][0]);

  float mrun[4], lrun[4];
  f32x4 o[4] = {};
  #pragma unroll
  for (int i=0;i<4;i++){ mrun[i] = -1e30f; lrun[i] = 0.f; }

  // prologue: stage tile 0, issue loads for tile 1
  bf16x8 kreg = *(const bf16x8*)kptr;
  bf16x8 vreg = *(const bf16x8*)vptr;
  *(bf16x8*)&Ks[0][kwoff] = kreg;
  *(bf16x8*)&Vs[0][vwoff] = vreg;
  kreg = *(const bf16x8*)(kptr + (size_t)64*QKVN);
  vreg = *(const bf16x8*)(vptr + (size_t)64*QKVN);

  const int NT = SEQL/64;   // 32
  for (int t=0; t<NT; t++){
    __syncthreads();
    if (t+1 < NT){
      *(bf16x8*)&Ks[(t+1)&1][kwoff] = kreg;
      *(bf16x8*)&Vs[(t+1)&1][vwoff] = vreg;
      if (t+2 < NT){
        kreg = *(const bf16x8*)(kptr + (size_t)(t+2)*64*QKVN);
        vreg = *(const bf16x8*)(vptr + (size_t)(t+2)*64*QKVN);
      }
    }
    const bf16_t* ksb = Ks[t&1];
    const u32 vs0 = ldsoff(&Vs[t&1][0]);

    // ---- S = (Q/8) K^T ----
    f32x4 s[4] = {};
    #pragma unroll
    for (int ks=0; ks<2; ks++){
      #pragma unroll
      for (int fn=0; fn<4; fn++){
        const int r = fn*16 + q16;
        const int ce = ks*32 + g*8;
        bf16x8 bk = *(const bf16x8*)&ksb[r*64 + (ce ^ ((r&7)<<3))];
        s[fn] = __builtin_amdgcn_mfma_f32_16x16x32_bf16(aq[ks], bk, s[fn], 0, 0, 0);
      }
    }

    // ---- online softmax (rows i; reduce over 16-lane group) ----
    #pragma unroll
    for (int i=0; i<4; i++){
      float s0=s[0][i], s1=s[1][i], s2=s[2][i], s3=s[3][i];
      float mx = fmaxf(fmaxf(s0,s1), fmaxf(s2,s3));
      #pragma unroll
      for (int m=1;m<16;m<<=1) mx = fmaxf(mx, __shfl_xor(mx,m));
      const float mnew = fmaxf(mrun[i], mx);
      const float alpha = __expf(mrun[i]-mnew);
      mrun[i] = mnew;
      s0=__expf(s0-mnew); s1=__expf(s1-mnew); s2=__expf(s2-mnew); s3=__expf(s3-mnew);
      s[0][i]=s0; s[1][i]=s1; s[2][i]=s2; s[3][i]=s3;
      float rs = (s0+s1)+(s2+s3);
      #pragma unroll
      for (int m=1;m<16;m<<=1) rs += __shfl_xor(rs,m);
      lrun[i] = lrun[i]*alpha + rs;
      #pragma unroll
      for (int ne=0;ne<4;ne++) o[ne][i] *= alpha;
    }

    // ---- P store: k-major subtiled, b64 per fn ----
    #pragma unroll
    for (int fn=0; fn<4; fn++){
      bf16x4 pv;
      #pragma unroll
      for (int i=0;i<4;i++) pv[i] = (__bf16)s[fn][i];
      *(bf16x4*)&PT[w][(fn*4 + (q16>>2))*72 + (lane&3)*16 + g*4] = pv;
    }

    // ---- O += P V  (tr-reads per ks half) ----
    #pragma unroll
    for (int ks=0; ks<2; ks++){
      const u32 pb = pt0 + (u32)(((ks*8 + 2*g)*72 + q16)*2);
      u32x2 plo = tr64(pb);
      u32x2 phi = tr64(pb + 144);
      u32x2 vlo[4], vhi[4];
      #pragma unroll
      for (int ne=0; ne<4; ne++){
        const u32 vb = vs0 + (u32)((((ks*8 + 2*g)*4 + ne)*72 + q16)*2);
        vlo[ne] = tr64(vb);
        vhi[ne] = tr64(vb + 576);
      }
      asm volatile("s_waitcnt lgkmcnt(0)" ::: "memory");
      __builtin_amdgcn_sched_barrier(0);
      union { u32x2 u[2]; bf16x8 v; } cc;
      cc.u[0]=plo; cc.u[1]=phi;
      const bf16x8 pa = cc.v;
      #pragma unroll
      for (int ne=0; ne<4; ne++){
        cc.u[0]=vlo[ne]; cc.u[1]=vhi[ne];
        o[ne] = __builtin_amdgcn_mfma_f32_16x16x32_bf16(pa, cc.v, o[ne], 0, 0, 0);
      }
    }
  }

  // ---- epilogue ----
  float rl[4];
  #pragma unroll
  for (int i=0;i<4;i++) rl[i] = 1.0f/lrun[i];
  #pragma unroll
  for (int ne=0; ne<4; ne++)
    #pragma unroll
    for (int i=0; i<4; i++){
      const int r = qr0 + g*4 + i;
      Ctx[(tok0+r)*DM + ch0 + ne*16 + q16] = (__bf16)(o[ne][i]*rl[i]);
    }
}

// ---------------- launcher ----------------
extern "C" void kernel_launch(void* const* d_in, const int* in_sizes, int n_in,
                              void* d_out, int out_size, void* d_ws, size_t ws_size,
                              hipStream_t stream)
{
  (void)in_sizes; (void)n_in; (void)out_size; (void)ws_size;
  const float* x  = (const float*)d_in[0];
  const float* wq = (const float*)d_in[1];
  const float* wk = (const float*)d_in[2];
  const float* wv = (const float*)d_in[3];
  const float* wo = (const float*)d_in[4];
  const float* w1 = (const float*)d_in[5];
  const float* w2 = (const float*)d_in[6];
  const float* g1 = (const float*)d_in[7];
  const float* b1 = (const float*)d_in[8];
  const float* g2 = (const float*)d_in[9];
  const float* b2 = (const float*)d_in[10];
  float* out = (float*)d_out;
  char* ws = (char*)d_ws;
  const size_t MB = 1024ull*1024ull;

  // ws layout (80 MB total, with aliasing):
  bf16_t* wqkv_b = (bf16_t*)(ws);            // 6 MB  [3072][1024]
  bf16_t* wo_b   = (bf16_t*)(ws + 6*MB);     // 2 MB
  bf16_t* w1_b   = (bf16_t*)(ws + 8*MB);     // 8 MB
  bf16_t* w2_b   = (bf16_t*)(ws + 16*MB);    // 8 MB
  bf16_t* h1     = (bf16_t*)(ws + 24*MB);    // 8 MB
  bf16_t* qkv    = (bf16_t*)(ws + 32*MB);    // 24 MB [4096][3072]
  bf16_t* ctx    = (bf16_t*)(ws + 56*MB);    // 8 MB
  float*  res2   = (float*)(ws + 64*MB);     // 16 MB
  bf16_t* h2     = h1;                       // alias: h1 dead after QKV GEMM
  bf16_t* ffm    = (bf16_t*)(ws + 32*MB);    // alias qkv+ctx: dead after WO GEMM

  // weights -> bf16 (QKV packed: q rows 0-1023, k 1024-2047, v 2048-3071)
  cvt_kernel<<<1024, 256, 0, stream>>>(wq, wqkv_b,            1024*1024);
  cvt_kernel<<<1024, 256, 0, stream>>>(wk, wqkv_b + 1024*1024, 1024*1024);
  cvt_kernel<<<1024, 256, 0, stream>>>(wv, wqkv_b + 2048*1024, 1024*1024);
  cvt_kernel<<<1024, 256, 0, stream>>>(wo, wo_b, 1024*1024);
  cvt_kernel<<<4096, 256, 0, stream>>>(w1, w1_b, 4096*1024);
  cvt_kernel<<<4096, 256, 0, stream>>>(w2, w2_b, 4096*1024);

  ln_kernel<<<NTOK, 256, 0, stream>>>(x, g1, b1, h1);
  gemm_bt<0,128><<<dim3(32, 24), 256, 0, stream>>>(h1, wqkv_b, (void*)qkv, nullptr, QKVN, 1024);
  attn_kernel<<<dim3(16, 32), 512, 0, stream>>>(qkv, ctx);
  gemm_bt<1,64><<<dim3(64, 8), 256, 0, stream>>>(ctx, wo_b, (void*)res2, x, 1024, 1024);
  ln_kernel<<<NTOK, 256, 0, stream>>>(res2, g2, b2, h2);
  gemm_bt<2,128><<<dim3(32, 32), 256, 0, stream>>>(h2, w1_b, (void*)ffm, nullptr, 4096, 1024);
  gemm_bt<1,64><<<dim3(64, 8), 256, 0, stream>>>(ffm, w2_b, (void*)out, x, 1024, 4096);
}

// Round 4
// 305.292 us; speedup vs baseline: 1.3566x; 1.0168x over previous
//
#include <hip/hip_runtime.h>
#include <hip/hip_bf16.h>
#include <math.h>

typedef __bf16 bf16_t;
typedef __bf16 bf16x8 __attribute__((ext_vector_type(8)));
typedef __bf16 bf16x4 __attribute__((ext_vector_type(4)));
typedef float f32x4 __attribute__((ext_vector_type(4)));
typedef unsigned int u32;
typedef u32 u32x2 __attribute__((ext_vector_type(2)));

#define DM 1024
#define SEQL 2048
#define NTOK 4096
#define QKVN 3072

__device__ __forceinline__ void gload_lds16(const bf16_t* g, bf16_t* l){
  __builtin_amdgcn_global_load_lds((const __attribute__((address_space(1))) void*)g,
                                   (__attribute__((address_space(3))) void*)l, 16, 0, 0);
}
__device__ __forceinline__ u32 ldsoff(const void* p){
  return (u32)(size_t)(__attribute__((address_space(3))) const void*)p;
}
__device__ __forceinline__ u32x2 tr64(u32 byte_off){
  u32x2 d;
  asm volatile("ds_read_b64_tr_b16 %0, %1" : "=v"(d) : "v"(byte_off));
  return d;
}

// ---------------- f32 -> bf16 convert (weights) ----------------
__global__ __launch_bounds__(256) void cvt_kernel(const float* __restrict__ src,
    bf16_t* __restrict__ dst, int n)
{
  const int i = (blockIdx.x*256 + threadIdx.x)*4;
  if (i < n){
    const float4 v = *(const float4*)(src + i);
    bf16x4 o; o[0]=(__bf16)v.x; o[1]=(__bf16)v.y; o[2]=(__bf16)v.z; o[3]=(__bf16)v.w;
    *(bf16x4*)(dst + i) = o;
  }
}

// ---------------- LayerNorm ----------------
__global__ __launch_bounds__(256) void ln_kernel(const float* __restrict__ in,
    const float* __restrict__ g, const float* __restrict__ bta,
    bf16_t* __restrict__ outp)
{
  const int row = blockIdx.x;
  const int t = threadIdx.x;
  const float4 v = *(const float4*)(in + (size_t)row*DM + t*4);
  float s  = v.x+v.y+v.z+v.w;
  float sq = v.x*v.x+v.y*v.y+v.z*v.z+v.w*v.w;
  #pragma unroll
  for (int m=1;m<64;m<<=1){ s += __shfl_xor(s,m); sq += __shfl_xor(sq,m); }
  __shared__ float red[8];
  const int w = t>>6;
  if ((t&63)==0){ red[w]=s; red[4+w]=sq; }
  __syncthreads();
  s  = red[0]+red[1]+red[2]+red[3];
  sq = red[4]+red[5]+red[6]+red[7];
  const float mean = s*(1.f/DM);
  const float var  = sq*(1.f/DM) - mean*mean;
  const float rstd = rsqrtf(var + 1e-5f);
  const float4 gg = *(const float4*)(g + t*4);
  const float4 bb = *(const float4*)(bta + t*4);
  bf16x4 o;
  o[0]=(__bf16)((v.x-mean)*rstd*gg.x+bb.x);
  o[1]=(__bf16)((v.y-mean)*rstd*gg.y+bb.y);
  o[2]=(__bf16)((v.z-mean)*rstd*gg.z+bb.z);
  o[3]=(__bf16)((v.w-mean)*rstd*gg.w+bb.w);
  *(bf16x4*)(outp + (size_t)row*DM + t*4) = o;
}

// ---------------- 256x256 phase-split GEMM, triple-buffered counted pipeline ------------
// C[M,N] = A[M,K](bf16) x Bw[N,K](bf16)^T.  EPI: 0 = bf16 store; 2 = bf16 gelu store.
// 8 waves (2m x 4n), per-wave 128x64 output. BK=32. LDS 3 x (A 16K + B 16K) = 96 KB.
// Tile t reads buf t%3 while tile t+2 stages into buf (t+2)%3; tile-end vmcnt(4)
// drains t+1's loads, keeps t+2's in flight (T4 counted, never 0 mid-loop).
template<int EPI>
__global__ __launch_bounds__(512, 2) void gemm256(
    const bf16_t* __restrict__ A, const bf16_t* __restrict__ Bw,
    void* __restrict__ Cout, int N, int K)
{
  constexpr int BK = 32;
  __shared__ __align__(16) char ldsb[3*32768];   // 96 KB
  const int tid = threadIdx.x, lane = tid&63, wid = tid>>6;
  const int q16 = lane&15, g = lane>>4;
  const int wm = wid>>2, wn = wid&3;
  const int bm = blockIdx.x*256, bn = blockIdx.y*256;

  // staging source mapping: linear LDS dest L=tid*16 holds logical element L^swz
  int mloc, kloc;
  {
    const u32 L = tid*16;
    const u32 logical = L ^ (((L>>9)&1)<<5);
    mloc = (int)((logical>>10)*16 + ((logical&1023)>>6));
    kloc = (int)((logical&63)>>1);
  }
  const bf16_t* asrc[2]; const bf16_t* bsrc[2];
  #pragma unroll
  for (int ht=0; ht<2; ht++){
    asrc[ht] = A  + (size_t)(bm + ht*128 + mloc)*K + kloc;
    bsrc[ht] = Bw + (size_t)(bn + ht*128 + mloc)*K + kloc;
  }
  const u32 laneOff = ((u32)(q16*64 + g*16)) ^ ((u32)(q16&8)<<2);

  f32x4 acc[8][4] = {};

  auto stageA = [&](int buf, int ht, int k0){
    gload_lds16(asrc[ht] + k0, (bf16_t*)(ldsb + buf*32768 + ht*8192 + tid*16));
  };
  auto stageB = [&](int buf, int ht, int k0){
    gload_lds16(bsrc[ht] + k0, (bf16_t*)(ldsb + buf*32768 + 16384 + ht*8192 + tid*16));
  };

  // prologue: stage tiles 0 and 1; wait for tile 0 only (tile 1 stays in flight)
  stageA(0,0,0); stageA(0,1,0); stageB(0,0,0); stageB(0,1,0);
  stageA(1,0,BK); stageA(1,1,BK); stageB(1,0,BK); stageB(1,1,BK);
  asm volatile("s_waitcnt vmcnt(4)" ::: "memory");
  __builtin_amdgcn_s_barrier();

  const int NT = K/BK;
  int bcur = 0;
  for (int kt=0; kt<NT; kt++){
    const int bstg = (bcur >= 1) ? bcur-1 : bcur+2;     // (bcur+2)%3
    const char* Ab = ldsb + bcur*32768 + wm*8192;
    const char* Bb = ldsb + bcur*32768 + 16384 + (wn>>1)*8192;
    const bool sOK = (kt+2 < NT);
    const int k0s = (kt+2)*BK;
    bf16x8 bv[4];
    #pragma unroll
    for (int p=0; p<2; p++){
      bf16x8 av[4];
      #pragma unroll
      for (int j=0;j<4;j++)
        av[j] = *(const bf16x8*)(Ab + ((p*4+j)<<10) + laneOff);
      if (p==0){
        #pragma unroll
        for (int j=0;j<4;j++)
          bv[j] = *(const bf16x8*)(Bb + ((((wn&1)*4)+j)<<10) + laneOff);
      }
      if (sOK){
        if (p==0){ stageA(bstg,0,k0s); stageA(bstg,1,k0s); }
        else     { stageB(bstg,0,k0s); stageB(bstg,1,k0s); }
      }
      asm volatile("s_barrier" ::: "memory");
      __builtin_amdgcn_s_setprio(1);
      #pragma unroll
      for (int j=0;j<4;j++)
        #pragma unroll
        for (int j2=0;j2<4;j2++)
          acc[p*4+j][j2] = __builtin_amdgcn_mfma_f32_16x16x32_bf16(av[j], bv[j2], acc[p*4+j][j2], 0,0,0);
      __builtin_amdgcn_s_setprio(0);
      if (p==1){
        if (sOK) asm volatile("s_waitcnt vmcnt(4)" ::: "memory");
        else     asm volatile("s_waitcnt vmcnt(0)" ::: "memory");  // tail drain
      }
      asm volatile("s_barrier" ::: "memory");
    }
    bcur = (bcur==2)?0:bcur+1;
  }

  #pragma unroll
  for (int fm=0; fm<8; fm++)
    #pragma unroll
    for (int fn=0; fn<4; fn++)
      #pragma unroll
      for (int i=0; i<4; i++){
        const int r = bm + wm*128 + fm*16 + g*4 + i;
        const int c = bn + wn*64 + fn*16 + q16;
        const size_t idx = (size_t)r*N + c;
        const float vv = acc[fm][fn][i];
        if constexpr (EPI==0){
          ((bf16_t*)Cout)[idx] = (__bf16)vv;
        } else {
          const float ge = 0.5f*vv*(1.0f + erff(vv*0.70710678118654752f));
          ((bf16_t*)Cout)[idx] = (__bf16)ge;
        }
      }
}

// ---------------- m97-style 128-tile GEMM (kept for N=1024 outputs: WO, FF2) -----------
// EPI: 1 = store fp32 (X + C)
template<int EPI, int BM>
__global__ __launch_bounds__(256) void gemm_bt(
    const bf16_t* __restrict__ A, const bf16_t* __restrict__ Bw,
    void* __restrict__ Cout, const float* __restrict__ X,
    int N, int K)
{
  constexpr int BN=128, BK=32;
  constexpr int FM = BM/32;
  __shared__ __align__(16) bf16_t As[2][BM][BK];
  __shared__ __align__(16) bf16_t Bs[2][BN][BK];
  const int tid = threadIdx.x, lane = tid&63, wid = tid>>6;
  const int bm = blockIdx.x*BM, bn = blockIdx.y*BN;
  const int wr = (wid>>1)*(BM/2), wc = (wid&1)*64;
  const int grow = lane>>2, gk = (lane&3)*8;

  f32x4 acc[FM][4] = {};

  const int NT = K/BK;
  auto stage = [&](int buf, int k0){
    #pragma unroll
    for (int c = wid; c < BM/16; c += 4)
      gload_lds16(A + (size_t)(bm + c*16 + grow)*K + k0 + gk, &As[buf][c*16][0]);
    #pragma unroll
    for (int c = wid; c < 8; c += 4)
      gload_lds16(Bw + (size_t)(bn + c*16 + grow)*K + k0 + gk, &Bs[buf][c*16][0]);
  };

  stage(0, 0);
  for (int t=0; t<NT; t++){
    __syncthreads();
    if (t+1 < NT) stage((t+1)&1, (t+1)*BK);
    const int b = t&1;
    bf16x8 af[FM], bfv[4];
    #pragma unroll
    for (int fm=0; fm<FM; fm++)
      af[fm] = *(const bf16x8*)&As[b][wr+fm*16+(lane&15)][(lane>>4)*8];
    #pragma unroll
    for (int fn=0; fn<4; fn++)
      bfv[fn] = *(const bf16x8*)&Bs[b][wc+fn*16+(lane&15)][(lane>>4)*8];
    #pragma unroll
    for (int fm=0; fm<FM; fm++)
      #pragma unroll
      for (int fn=0; fn<4; fn++)
        acc[fm][fn] = __builtin_amdgcn_mfma_f32_16x16x32_bf16(af[fm], bfv[fn], acc[fm][fn], 0, 0, 0);
  }

  #pragma unroll
  for (int fm=0; fm<FM; fm++)
    #pragma unroll
    for (int fn=0; fn<4; fn++)
      #pragma unroll
      for (int i=0; i<4; i++){
        const int r = bm + wr + fm*16 + (lane>>4)*4 + i;
        const int c = bn + wc + fn*16 + (lane&15);
        const size_t idx = (size_t)r*N + c;
        const float vv = acc[fm][fn][i];
        if constexpr (EPI==1){
          ((float*)Cout)[idx] = X[idx] + vv;
        } else {
          ((bf16_t*)Cout)[idx] = (__bf16)vv;
        }
      }
}

// ---------------- Flash attention (unchanged) ----------------
__global__ __launch_bounds__(512, 4) void attn_kernel(
    const bf16_t* __restrict__ QKV, bf16_t* __restrict__ Ctx)
{
  __shared__ __align__(16) bf16_t Ks[2][64*64];
  __shared__ __align__(16) bf16_t Vs[2][16*4*72];
  __shared__ __align__(16) bf16_t PT[8][16*72];
  const int tid = threadIdx.x, lane = tid&63, w = tid>>6;
  const int g = lane>>4, q16 = lane&15;
  const int bh = blockIdx.y, b = bh>>4, h = bh&15;
  const int qr0 = blockIdx.x*128 + w*16;
  const size_t tok0 = (size_t)b*SEQL;
  const int ch0 = h*64;

  bf16x8 aq[2];
  #pragma unroll
  for (int ks=0; ks<2; ks++){
    bf16x8 t = *(const bf16x8*)(QKV + (tok0+qr0+q16)*QKVN + ch0 + ks*32 + g*8);
    #pragma unroll
    for (int j=0;j<8;j++) t[j] = (__bf16)((float)t[j]*0.125f);
    aq[ks] = t;
  }

  const int srow = tid>>3, sc8 = (tid&7)*8;
  const bf16_t* kptr = QKV + (tok0+srow)*QKVN + 1024 + ch0 + sc8;
  const bf16_t* vptr = kptr + 1024;
  const int kwoff = srow*64 + (sc8 ^ ((srow&7)<<3));
  const int vwoff = ((srow>>2)*4 + (sc8>>4))*72 + (srow&3)*16 + (sc8&15);

  const u32 pt0 = ldsoff(&PT[w][0]);

  float mrun[4], lrun[4];
  f32x4 o[4] = {};
  #pragma unroll
  for (int i=0;i<4;i++){ mrun[i] = -1e30f; lrun[i] = 0.f; }

  bf16x8 kreg = *(const bf16x8*)kptr;
  bf16x8 vreg = *(const bf16x8*)vptr;
  *(bf16x8*)&Ks[0][kwoff] = kreg;
  *(bf16x8*)&Vs[0][vwoff] = vreg;
  kreg = *(const bf16x8*)(kptr + (size_t)64*QKVN);
  vreg = *(const bf16x8*)(vptr + (size_t)64*QKVN);

  const int NT = SEQL/64;
  for (int t=0; t<NT; t++){
    __syncthreads();
    if (t+1 < NT){
      *(bf16x8*)&Ks[(t+1)&1][kwoff] = kreg;
      *(bf16x8*)&Vs[(t+1)&1][vwoff] = vreg;
      if (t+2 < NT){
        kreg = *(const bf16x8*)(kptr + (size_t)(t+2)*64*QKVN);
        vreg = *(const bf16x8*)(vptr + (size_t)(t+2)*64*QKVN);
      }
    }
    const bf16_t* ksb = Ks[t&1];
    const u32 vs0 = ldsoff(&Vs[t&1][0]);

    f32x4 s[4] = {};
    #pragma unroll
    for (int ks=0; ks<2; ks++){
      #pragma unroll
      for (int fn=0; fn<4; fn++){
        const int r = fn*16 + q16;
        const int ce = ks*32 + g*8;
        bf16x8 bk = *(const bf16x8*)&ksb[r*64 + (ce ^ ((r&7)<<3))];
        s[fn] = __builtin_amdgcn_mfma_f32_16x16x32_bf16(aq[ks], bk, s[fn], 0, 0, 0);
      }
    }

    #pragma unroll
    for (int i=0; i<4; i++){
      float s0=s[0][i], s1=s[1][i], s2=s[2][i], s3=s[3][i];
      float mx = fmaxf(fmaxf(s0,s1), fmaxf(s2,s3));
      #pragma unroll
      for (int m=1;m<16;m<<=1) mx = fmaxf(mx, __shfl_xor(mx,m));
      const float mnew = fmaxf(mrun[i], mx);
      const float alpha = __expf(mrun[i]-mnew);
      mrun[i] = mnew;
      s0=__expf(s0-mnew); s1=__expf(s1-mnew); s2=__expf(s2-mnew); s3=__expf(s3-mnew);
      s[0][i]=s0; s[1][i]=s1; s[2][i]=s2; s[3][i]=s3;
      float rs = (s0+s1)+(s2+s3);
      #pragma unroll
      for (int m=1;m<16;m<<=1) rs += __shfl_xor(rs,m);
      lrun[i] = lrun[i]*alpha + rs;
      #pragma unroll
      for (int ne=0;ne<4;ne++) o[ne][i] *= alpha;
    }

    #pragma unroll
    for (int fn=0; fn<4; fn++){
      bf16x4 pv;
      #pragma unroll
      for (int i=0;i<4;i++) pv[i] = (__bf16)s[fn][i];
      *(bf16x4*)&PT[w][(fn*4 + (q16>>2))*72 + (lane&3)*16 + g*4] = pv;
    }

    #pragma unroll
    for (int ks=0; ks<2; ks++){
      const u32 pb = pt0 + (u32)(((ks*8 + 2*g)*72 + q16)*2);
      u32x2 plo = tr64(pb);
      u32x2 phi = tr64(pb + 144);
      u32x2 vlo[4], vhi[4];
      #pragma unroll
      for (int ne=0; ne<4; ne++){
        const u32 vb = vs0 + (u32)((((ks*8 + 2*g)*4 + ne)*72 + q16)*2);
        vlo[ne] = tr64(vb);
        vhi[ne] = tr64(vb + 576);
      }
      asm volatile("s_waitcnt lgkmcnt(0)" ::: "memory");
      __builtin_amdgcn_sched_barrier(0);
      union { u32x2 u[2]; bf16x8 v; } cc;
      cc.u[0]=plo; cc.u[1]=phi;
      const bf16x8 pa = cc.v;
      #pragma unroll
      for (int ne=0; ne<4; ne++){
        cc.u[0]=vlo[ne]; cc.u[1]=vhi[ne];
        o[ne] = __builtin_amdgcn_mfma_f32_16x16x32_bf16(pa, cc.v, o[ne], 0, 0, 0);
      }
    }
  }

  float rl[4];
  #pragma unroll
  for (int i=0;i<4;i++) rl[i] = 1.0f/lrun[i];
  #pragma unroll
  for (int ne=0; ne<4; ne++)
    #pragma unroll
    for (int i=0; i<4; i++){
      const int r = qr0 + g*4 + i;
      Ctx[(tok0+r)*DM + ch0 + ne*16 + q16] = (__bf16)(o[ne][i]*rl[i]);
    }
}

// ---------------- launcher ----------------
extern "C" void kernel_launch(void* const* d_in, const int* in_sizes, int n_in,
                              void* d_out, int out_size, void* d_ws, size_t ws_size,
                              hipStream_t stream)
{
  (void)in_sizes; (void)n_in; (void)out_size; (void)ws_size;
  const float* x  = (const float*)d_in[0];
  const float* wq = (const float*)d_in[1];
  const float* wk = (const float*)d_in[2];
  const float* wv = (const float*)d_in[3];
  const float* wo = (const float*)d_in[4];
  const float* w1 = (const float*)d_in[5];
  const float* w2 = (const float*)d_in[6];
  const float* g1 = (const float*)d_in[7];
  const float* b1 = (const float*)d_in[8];
  const float* g2 = (const float*)d_in[9];
  const float* b2 = (const float*)d_in[10];
  float* out = (float*)d_out;
  char* ws = (char*)d_ws;
  const size_t MB = 1024ull*1024ull;

  bf16_t* wqkv_b = (bf16_t*)(ws);            // 6 MB  [3072][1024]
  bf16_t* wo_b   = (bf16_t*)(ws + 6*MB);     // 2 MB
  bf16_t* w1_b   = (bf16_t*)(ws + 8*MB);     // 8 MB
  bf16_t* w2_b   = (bf16_t*)(ws + 16*MB);    // 8 MB
  bf16_t* h1     = (bf16_t*)(ws + 24*MB);    // 8 MB
  bf16_t* qkv    = (bf16_t*)(ws + 32*MB);    // 24 MB [4096][3072]
  bf16_t* ctx    = (bf16_t*)(ws + 56*MB);    // 8 MB
  float*  res2   = (float*)(ws + 64*MB);     // 16 MB
  bf16_t* h2     = h1;                       // alias: h1 dead after QKV GEMM
  bf16_t* ffm    = (bf16_t*)(ws + 32*MB);    // alias qkv+ctx (dead by then)

  cvt_kernel<<<1024, 256, 0, stream>>>(wq, wqkv_b,             1024*1024);
  cvt_kernel<<<1024, 256, 0, stream>>>(wk, wqkv_b + 1024*1024, 1024*1024);
  cvt_kernel<<<1024, 256, 0, stream>>>(wv, wqkv_b + 2048*1024, 1024*1024);
  cvt_kernel<<<1024, 256, 0, stream>>>(wo, wo_b, 1024*1024);
  cvt_kernel<<<4096, 256, 0, stream>>>(w1, w1_b, 4096*1024);
  cvt_kernel<<<4096, 256, 0, stream>>>(w2, w2_b, 4096*1024);

  ln_kernel<<<NTOK, 256, 0, stream>>>(x, g1, b1, h1);
  gemm256<0><<<dim3(16, 12), 512, 0, stream>>>(h1, wqkv_b, (void*)qkv, QKVN, 1024);
  attn_kernel<<<dim3(16, 32), 512, 0, stream>>>(qkv, ctx);
  gemm_bt<1,64><<<dim3(64, 8), 256, 0, stream>>>(ctx, wo_b, (void*)res2, x, 1024, 1024);
  ln_kernel<<<NTOK, 256, 0, stream>>>(res2, g2, b2, h2);
  gemm256<2><<<dim3(16, 16), 512, 0, stream>>>(h2, w1_b, (void*)ffm, 4096, 1024);
  gemm_bt<1,64><<<dim3(64, 8), 256, 0, stream>>>(ffm, w2_b, (void*)out, x, 1024, 4096);
}

// Round 5
// 285.831 us; speedup vs baseline: 1.4490x; 1.0681x over previous
//
#include <hip/hip_runtime.h>
#include <hip/hip_bf16.h>
#include <math.h>

typedef __bf16 bf16_t;
typedef __bf16 bf16x8 __attribute__((ext_vector_type(8)));
typedef __bf16 bf16x4 __attribute__((ext_vector_type(4)));
typedef float f32x4 __attribute__((ext_vector_type(4)));
typedef unsigned int u32;
typedef u32 u32x2 __attribute__((ext_vector_type(2)));

#define DM 1024
#define SEQL 2048
#define NTOK 4096
#define QKVN 3072

__device__ __forceinline__ void gload_lds16(const bf16_t* g, bf16_t* l){
  __builtin_amdgcn_global_load_lds((const __attribute__((address_space(1))) void*)g,
                                   (__attribute__((address_space(3))) void*)l, 16, 0, 0);
}
__device__ __forceinline__ u32 ldsoff(const void* p){
  return (u32)(size_t)(__attribute__((address_space(3))) const void*)p;
}
__device__ __forceinline__ u32x2 tr64(u32 byte_off){
  u32x2 d;
  asm volatile("ds_read_b64_tr_b16 %0, %1" : "=v"(d) : "v"(byte_off));
  return d;
}
__device__ __forceinline__ u32 pack2(float a, float b){
  union{ __bf16 h[2]; u32 w; } z;
  z.h[0]=(__bf16)a; z.h[1]=(__bf16)b; return z.w;
}

// ---------------- f32 -> bf16 convert (weights) ----------------
__global__ __launch_bounds__(256) void cvt_kernel(const float* __restrict__ src,
    bf16_t* __restrict__ dst, int n)
{
  const int i = (blockIdx.x*256 + threadIdx.x)*4;
  if (i < n){
    const float4 v = *(const float4*)(src + i);
    bf16x4 o; o[0]=(__bf16)v.x; o[1]=(__bf16)v.y; o[2]=(__bf16)v.z; o[3]=(__bf16)v.w;
    *(bf16x4*)(dst + i) = o;
  }
}

// ---------------- LayerNorm ----------------
__global__ __launch_bounds__(256) void ln_kernel(const float* __restrict__ in,
    const float* __restrict__ g, const float* __restrict__ bta,
    bf16_t* __restrict__ outp)
{
  const int row = blockIdx.x;
  const int t = threadIdx.x;
  const float4 v = *(const float4*)(in + (size_t)row*DM + t*4);
  float s  = v.x+v.y+v.z+v.w;
  float sq = v.x*v.x+v.y*v.y+v.z*v.z+v.w*v.w;
  #pragma unroll
  for (int m=1;m<64;m<<=1){ s += __shfl_xor(s,m); sq += __shfl_xor(sq,m); }
  __shared__ float red[8];
  const int w = t>>6;
  if ((t&63)==0){ red[w]=s; red[4+w]=sq; }
  __syncthreads();
  s  = red[0]+red[1]+red[2]+red[3];
  sq = red[4]+red[5]+red[6]+red[7];
  const float mean = s*(1.f/DM);
  const float var  = sq*(1.f/DM) - mean*mean;
  const float rstd = rsqrtf(var + 1e-5f);
  const float4 gg = *(const float4*)(g + t*4);
  const float4 bb = *(const float4*)(bta + t*4);
  bf16x4 o;
  o[0]=(__bf16)((v.x-mean)*rstd*gg.x+bb.x);
  o[1]=(__bf16)((v.y-mean)*rstd*gg.y+bb.y);
  o[2]=(__bf16)((v.z-mean)*rstd*gg.z+bb.z);
  o[3]=(__bf16)((v.w-mean)*rstd*gg.w+bb.w);
  *(bf16x4*)(outp + (size_t)row*DM + t*4) = o;
}

// ---------------- 256x256 phase-split GEMM, triple-buffered counted pipeline ------------
// XCD-pinned mapping: XCD k owns 2 bm-panels (A resident in L2), sweeps all bn.
template<int EPI>
__global__ __launch_bounds__(512, 2) void gemm256(
    const bf16_t* __restrict__ A, const bf16_t* __restrict__ Bw,
    void* __restrict__ Cout, int N, int K)
{
  constexpr int BK = 32;
  __shared__ __align__(16) char ldsb[3*32768];   // 96 KB
  const int tid = threadIdx.x, lane = tid&63, wid = tid>>6;
  const int q16 = lane&15, g = lane>>4;
  const int wm = wid>>2, wn = wid&3;

  // XCD-pinned tile mapping (gridDim.x == 16, nwg % 8 == 0)
  const int flat = blockIdx.y*gridDim.x + blockIdx.x;
  const int xcd = flat&7, j = flat>>3;
  const int NY = gridDim.y;
  const int jdiv = j/NY, jmod = j - jdiv*NY;
  const int bm = (xcd*2 + jdiv)*256, bn = jmod*256;

  // staging source mapping: linear LDS dest L=tid*16 holds logical element L^swz
  int mloc, kloc;
  {
    const u32 L = tid*16;
    const u32 logical = L ^ (((L>>9)&1)<<5);
    mloc = (int)((logical>>10)*16 + ((logical&1023)>>6));
    kloc = (int)((logical&63)>>1);
  }
  const bf16_t* asrc[2]; const bf16_t* bsrc[2];
  #pragma unroll
  for (int ht=0; ht<2; ht++){
    asrc[ht] = A  + (size_t)(bm + ht*128 + mloc)*K + kloc;
    bsrc[ht] = Bw + (size_t)(bn + ht*128 + mloc)*K + kloc;
  }
  const u32 laneOff = ((u32)(q16*64 + g*16)) ^ ((u32)(q16&8)<<2);

  f32x4 acc[8][4] = {};

  auto stageA = [&](int buf, int ht, int k0){
    gload_lds16(asrc[ht] + k0, (bf16_t*)(ldsb + buf*32768 + ht*8192 + tid*16));
  };
  auto stageB = [&](int buf, int ht, int k0){
    gload_lds16(bsrc[ht] + k0, (bf16_t*)(ldsb + buf*32768 + 16384 + ht*8192 + tid*16));
  };

  stageA(0,0,0); stageA(0,1,0); stageB(0,0,0); stageB(0,1,0);
  stageA(1,0,BK); stageA(1,1,BK); stageB(1,0,BK); stageB(1,1,BK);
  asm volatile("s_waitcnt vmcnt(4)" ::: "memory");
  __builtin_amdgcn_s_barrier();

  const int NT = K/BK;
  int bcur = 0;
  for (int kt=0; kt<NT; kt++){
    const int bstg = (bcur >= 1) ? bcur-1 : bcur+2;     // (bcur+2)%3
    const char* Ab = ldsb + bcur*32768 + wm*8192;
    const char* Bb = ldsb + bcur*32768 + 16384 + (wn>>1)*8192;
    const bool sOK = (kt+2 < NT);
    const int k0s = (kt+2)*BK;
    bf16x8 bv[4];
    #pragma unroll
    for (int p=0; p<2; p++){
      bf16x8 av[4];
      #pragma unroll
      for (int jx=0;jx<4;jx++)
        av[jx] = *(const bf16x8*)(Ab + ((p*4+jx)<<10) + laneOff);
      if (p==0){
        #pragma unroll
        for (int jx=0;jx<4;jx++)
          bv[jx] = *(const bf16x8*)(Bb + ((((wn&1)*4)+jx)<<10) + laneOff);
      }
      if (sOK){
        if (p==0){ stageA(bstg,0,k0s); stageA(bstg,1,k0s); }
        else     { stageB(bstg,0,k0s); stageB(bstg,1,k0s); }
      }
      asm volatile("s_barrier" ::: "memory");
      __builtin_amdgcn_s_setprio(1);
      #pragma unroll
      for (int jx=0;jx<4;jx++)
        #pragma unroll
        for (int j2=0;j2<4;j2++)
          acc[p*4+jx][j2] = __builtin_amdgcn_mfma_f32_16x16x32_bf16(av[jx], bv[j2], acc[p*4+jx][j2], 0,0,0);
      __builtin_amdgcn_s_setprio(0);
      if (p==1){
        if (sOK) asm volatile("s_waitcnt vmcnt(4)" ::: "memory");
        else     asm volatile("s_waitcnt vmcnt(0)" ::: "memory");
      }
      asm volatile("s_barrier" ::: "memory");
    }
    bcur = (bcur==2)?0:bcur+1;
  }

  #pragma unroll
  for (int fm=0; fm<8; fm++)
    #pragma unroll
    for (int fn=0; fn<4; fn++)
      #pragma unroll
      for (int i=0; i<4; i++){
        const int r = bm + wm*128 + fm*16 + g*4 + i;
        const int c = bn + wn*64 + fn*16 + q16;
        const size_t idx = (size_t)r*N + c;
        const float vv = acc[fm][fn][i];
        if constexpr (EPI==0){
          ((bf16_t*)Cout)[idx] = (__bf16)vv;
        } else {
          const float ge = 0.5f*vv*(1.0f + erff(vv*0.70710678118654752f));
          ((bf16_t*)Cout)[idx] = (__bf16)ge;
        }
      }
}

// ---------------- m97-style 128x64 GEMM for N=1024 outputs (WO, FF2) -----------
// MAP 1 (WO):  XCD k owns bm 8k..8k+7; B (2MB) fully L2-resident per XCD.
// MAP 2 (FF2): XCD k owns bn-pair {2(k&3),+1} (L2-resident) + bm-half; A streams once.
template<int EPI, int BM, int MAP>
__global__ __launch_bounds__(256) void gemm_bt(
    const bf16_t* __restrict__ A, const bf16_t* __restrict__ Bw,
    void* __restrict__ Cout, const float* __restrict__ X,
    int N, int K)
{
  constexpr int BN=128, BK=32;
  constexpr int FM = BM/32;
  __shared__ __align__(16) bf16_t As[2][BM][BK];
  __shared__ __align__(16) bf16_t Bs[2][BN][BK];
  const int tid = threadIdx.x, lane = tid&63, wid = tid>>6;

  int bxi, byi;
  if constexpr (MAP==0){ bxi = blockIdx.x; byi = blockIdx.y; }
  else {
    const int flat = blockIdx.y*gridDim.x + blockIdx.x;
    const int xcd = flat&7, j = flat>>3;
    if constexpr (MAP==1){ bxi = (xcd<<3) + (j>>3); byi = j&7; }
    else                 { bxi = ((xcd>>2)<<5) + (j>>1); byi = ((xcd&3)<<1) + (j&1); }
  }
  const int bm = bxi*BM, bn = byi*BN;
  const int wr = (wid>>1)*(BM/2), wc = (wid&1)*64;
  const int grow = lane>>2, gk = (lane&3)*8;

  f32x4 acc[FM][4] = {};

  const int NT = K/BK;
  auto stage = [&](int buf, int k0){
    #pragma unroll
    for (int c = wid; c < BM/16; c += 4)
      gload_lds16(A + (size_t)(bm + c*16 + grow)*K + k0 + gk, &As[buf][c*16][0]);
    #pragma unroll
    for (int c = wid; c < 8; c += 4)
      gload_lds16(Bw + (size_t)(bn + c*16 + grow)*K + k0 + gk, &Bs[buf][c*16][0]);
  };

  stage(0, 0);
  for (int t=0; t<NT; t++){
    __syncthreads();
    if (t+1 < NT) stage((t+1)&1, (t+1)*BK);
    const int b = t&1;
    bf16x8 af[FM], bfv[4];
    #pragma unroll
    for (int fm=0; fm<FM; fm++)
      af[fm] = *(const bf16x8*)&As[b][wr+fm*16+(lane&15)][(lane>>4)*8];
    #pragma unroll
    for (int fn=0; fn<4; fn++)
      bfv[fn] = *(const bf16x8*)&Bs[b][wc+fn*16+(lane&15)][(lane>>4)*8];
    #pragma unroll
    for (int fm=0; fm<FM; fm++)
      #pragma unroll
      for (int fn=0; fn<4; fn++)
        acc[fm][fn] = __builtin_amdgcn_mfma_f32_16x16x32_bf16(af[fm], bfv[fn], acc[fm][fn], 0, 0, 0);
  }

  #pragma unroll
  for (int fm=0; fm<FM; fm++)
    #pragma unroll
    for (int fn=0; fn<4; fn++)
      #pragma unroll
      for (int i=0; i<4; i++){
        const int r = bm + wr + fm*16 + (lane>>4)*4 + i;
        const int c = bn + wc + fn*16 + (lane&15);
        const size_t idx = (size_t)r*N + c;
        const float vv = acc[fm][fn][i];
        if constexpr (EPI==1){
          ((float*)Cout)[idx] = X[idx] + vv;
        } else {
          ((bf16_t*)Cout)[idx] = (__bf16)vv;
        }
      }
}

// ---------------- Flash attention v3: swapped QK^T + in-register softmax ----------------
// 512 thr, 8 waves x 16 q-rows. S^T = mfma(K,Q): lane(q=lane&15,g) holds
// P[k=fn*16+g*4+i][q] -> softmax reductions in-register + 2 shfl_xor.
// P distributed to PV A-frags via 16 shfl + 8 cndmask (no LDS round-trip).
__global__ __launch_bounds__(512, 4) void attn_kernel(
    const bf16_t* __restrict__ QKV, bf16_t* __restrict__ Ctx)
{
  __shared__ __align__(16) bf16_t Ks[2][64*64];
  __shared__ __align__(16) bf16_t Vs[2][16*4*72];
  const int tid = threadIdx.x, lane = tid&63, w = tid>>6;
  const int g = lane>>4, q16 = lane&15;
  const int bh = blockIdx.y, b = bh>>4, h = bh&15;
  const int qr0 = blockIdx.x*128 + w*16;
  const size_t tok0 = (size_t)b*SEQL;
  const int ch0 = h*64;

  // Q fragments, pre-scaled by 1/sqrt(64)=0.125 (exact in bf16)
  bf16x8 aq[2];
  #pragma unroll
  for (int ks=0; ks<2; ks++){
    bf16x8 t = *(const bf16x8*)(QKV + (tok0+qr0+q16)*QKVN + ch0 + ks*32 + g*8);
    #pragma unroll
    for (int jx=0;jx<8;jx++) t[jx] = (__bf16)((float)t[jx]*0.125f);
    aq[ks] = t;
  }

  const int srow = tid>>3, sc8 = (tid&7)*8;
  const bf16_t* kptr = QKV + (tok0+srow)*QKVN + 1024 + ch0 + sc8;
  const bf16_t* vptr = kptr + 1024;
  const int kwoff = srow*64 + (sc8 ^ ((srow&7)<<3));
  const int vwoff = ((srow>>2)*4 + (sc8>>4))*72 + (srow&3)*16 + (sc8&15);

  float mrun = -1e30f, lrun = 0.f;    // state for q = q16 (agreed across g)
  f32x4 o[4] = {};

  bf16x8 kreg = *(const bf16x8*)kptr;
  bf16x8 vreg = *(const bf16x8*)vptr;
  *(bf16x8*)&Ks[0][kwoff] = kreg;
  *(bf16x8*)&Vs[0][vwoff] = vreg;
  kreg = *(const bf16x8*)(kptr + (size_t)64*QKVN);
  vreg = *(const bf16x8*)(vptr + (size_t)64*QKVN);

  const int NT = SEQL/64;
  for (int t=0; t<NT; t++){
    __syncthreads();
    if (t+1 < NT){
      *(bf16x8*)&Ks[(t+1)&1][kwoff] = kreg;
      *(bf16x8*)&Vs[(t+1)&1][vwoff] = vreg;
      if (t+2 < NT){
        kreg = *(const bf16x8*)(kptr + (size_t)(t+2)*64*QKVN);
        vreg = *(const bf16x8*)(vptr + (size_t)(t+2)*64*QKVN);
      }
    }
    const bf16_t* ksb = Ks[t&1];
    const u32 vs0 = ldsoff(&Vs[t&1][0]);

    // ---- S^T = K (Q/8)^T : swapped operands ----
    f32x4 s[4] = {};
    #pragma unroll
    for (int ks=0; ks<2; ks++){
      #pragma unroll
      for (int fn=0; fn<4; fn++){
        const int r = fn*16 + q16;
        const int ce = ks*32 + g*8;
        bf16x8 bk = *(const bf16x8*)&ksb[r*64 + (ce ^ ((r&7)<<3))];
        s[fn] = __builtin_amdgcn_mfma_f32_16x16x32_bf16(bk, aq[ks], s[fn], 0, 0, 0);
      }
    }

    // ---- in-register online softmax (lane owns row q16; 16 vals) ----
    float m0 = fmaxf(fmaxf(s[0][0],s[0][1]), fmaxf(s[0][2],s[0][3]));
    float m1 = fmaxf(fmaxf(s[1][0],s[1][1]), fmaxf(s[1][2],s[1][3]));
    float m2 = fmaxf(fmaxf(s[2][0],s[2][1]), fmaxf(s[2][2],s[2][3]));
    float m3 = fmaxf(fmaxf(s[3][0],s[3][1]), fmaxf(s[3][2],s[3][3]));
    float mx = fmaxf(fmaxf(m0,m1), fmaxf(m2,m3));
    mx = fmaxf(mx, __shfl_xor(mx,16));
    mx = fmaxf(mx, __shfl_xor(mx,32));

    if (!__all(mx <= mrun + 8.0f)){          // defer-max (T13)
      const float mnew = fmaxf(mrun, mx);
      const float alpha = __expf(mrun - mnew);
      #pragma unroll
      for (int i=0;i<4;i++){
        const float ai = __shfl(alpha, g*4+i);   // O rows are q=g*4+i
        o[0][i]*=ai; o[1][i]*=ai; o[2][i]*=ai; o[3][i]*=ai;
      }
      lrun *= alpha;
      mrun = mnew;
    }

    float rs = 0.f;
    u32 u[4][2];
    #pragma unroll
    for (int fn=0; fn<4; fn++){
      const float e0=__expf(s[fn][0]-mrun), e1=__expf(s[fn][1]-mrun);
      const float e2=__expf(s[fn][2]-mrun), e3=__expf(s[fn][3]-mrun);
      rs += (e0+e1)+(e2+e3);
      u[fn][0] = pack2(e0,e1);
      u[fn][1] = pack2(e2,e3);
    }
    rs += __shfl_xor(rs,16);
    rs += __shfl_xor(rs,32);
    lrun += rs;

    // ---- O += P V ----
    #pragma unroll
    for (int ks=0; ks<2; ks++){
      u32x2 vlo[4], vhi[4];
      #pragma unroll
      for (int ne=0; ne<4; ne++){
        const u32 vb = vs0 + (u32)((((ks*8 + 2*g)*4 + ne)*72 + q16)*2);
        vlo[ne] = tr64(vb);
        vhi[ne] = tr64(vb + 576);
      }
      // build P A-frag: elem j holds P[q16][32ks+8g+j]
      union { u32 wd[4]; bf16x8 v; } pa;
      #pragma unroll
      for (int jj=0; jj<4; jj++){
        const int src = q16 + ((((g&1)<<1) + (jj>>1))<<4);
        const u32 a0 = (u32)__shfl((int)u[2*ks  ][jj&1], src);
        const u32 a1 = (u32)__shfl((int)u[2*ks+1][jj&1], src);
        pa.wd[jj] = (g&2) ? a1 : a0;
      }
      asm volatile("s_waitcnt lgkmcnt(0)" ::: "memory");
      __builtin_amdgcn_sched_barrier(0);
      union { u32x2 u2[2]; bf16x8 v; } cc;
      #pragma unroll
      for (int ne=0; ne<4; ne++){
        cc.u2[0]=vlo[ne]; cc.u2[1]=vhi[ne];
        o[ne] = __builtin_amdgcn_mfma_f32_16x16x32_bf16(pa.v, cc.v, o[ne], 0, 0, 0);
      }
    }
  }

  // ---- epilogue: rows q = g*4+i need 1/l of that row ----
  const float rl = 1.0f/lrun;
  #pragma unroll
  for (int i=0; i<4; i++){
    const float ri = __shfl(rl, g*4+i);
    #pragma unroll
    for (int ne=0; ne<4; ne++){
      const int r = qr0 + g*4 + i;
      Ctx[(tok0+r)*DM + ch0 + ne*16 + q16] = (__bf16)(o[ne][i]*ri);
    }
  }
}

// ---------------- launcher ----------------
extern "C" void kernel_launch(void* const* d_in, const int* in_sizes, int n_in,
                              void* d_out, int out_size, void* d_ws, size_t ws_size,
                              hipStream_t stream)
{
  (void)in_sizes; (void)n_in; (void)out_size; (void)ws_size;
  const float* x  = (const float*)d_in[0];
  const float* wq = (const float*)d_in[1];
  const float* wk = (const float*)d_in[2];
  const float* wv = (const float*)d_in[3];
  const float* wo = (const float*)d_in[4];
  const float* w1 = (const float*)d_in[5];
  const float* w2 = (const float*)d_in[6];
  const float* g1 = (const float*)d_in[7];
  const float* b1 = (const float*)d_in[8];
  const float* g2 = (const float*)d_in[9];
  const float* b2 = (const float*)d_in[10];
  float* out = (float*)d_out;
  char* ws = (char*)d_ws;
  const size_t MB = 1024ull*1024ull;

  bf16_t* wqkv_b = (bf16_t*)(ws);            // 6 MB  [3072][1024]
  bf16_t* wo_b   = (bf16_t*)(ws + 6*MB);     // 2 MB
  bf16_t* w1_b   = (bf16_t*)(ws + 8*MB);     // 8 MB
  bf16_t* w2_b   = (bf16_t*)(ws + 16*MB);    // 8 MB
  bf16_t* h1     = (bf16_t*)(ws + 24*MB);    // 8 MB
  bf16_t* qkv    = (bf16_t*)(ws + 32*MB);    // 24 MB [4096][3072]
  bf16_t* ctx    = (bf16_t*)(ws + 56*MB);    // 8 MB
  float*  res2   = (float*)(ws + 64*MB);     // 16 MB
  bf16_t* h2     = h1;                       // alias: h1 dead after QKV GEMM
  bf16_t* ffm    = (bf16_t*)(ws + 32*MB);    // alias qkv+ctx (dead by then)

  cvt_kernel<<<1024, 256, 0, stream>>>(wq, wqkv_b,             1024*1024);
  cvt_kernel<<<1024, 256, 0, stream>>>(wk, wqkv_b + 1024*1024, 1024*1024);
  cvt_kernel<<<1024, 256, 0, stream>>>(wv, wqkv_b + 2048*1024, 1024*1024);
  cvt_kernel<<<1024, 256, 0, stream>>>(wo, wo_b, 1024*1024);
  cvt_kernel<<<4096, 256, 0, stream>>>(w1, w1_b, 4096*1024);
  cvt_kernel<<<4096, 256, 0, stream>>>(w2, w2_b, 4096*1024);

  ln_kernel<<<NTOK, 256, 0, stream>>>(x, g1, b1, h1);
  gemm256<0><<<dim3(16, 12), 512, 0, stream>>>(h1, wqkv_b, (void*)qkv, QKVN, 1024);
  attn_kernel<<<dim3(16, 32), 512, 0, stream>>>(qkv, ctx);
  gemm_bt<1,64,1><<<dim3(64, 8), 256, 0, stream>>>(ctx, wo_b, (void*)res2, x, 1024, 1024);
  ln_kernel<<<NTOK, 256, 0, stream>>>(res2, g2, b2, h2);
  gemm256<2><<<dim3(16, 16), 512, 0, stream>>>(h2, w1_b, (void*)ffm, 4096, 1024);
  gemm_bt<1,64,2><<<dim3(64, 8), 256, 0, stream>>>(ffm, w2_b, (void*)out, x, 1024, 4096);
}

// Round 6
// 260.993 us; speedup vs baseline: 1.5869x; 1.0952x over previous
//
#include <hip/hip_runtime.h>
#include <hip/hip_bf16.h>
#include <math.h>

typedef __bf16 bf16_t;
typedef __bf16 bf16x8 __attribute__((ext_vector_type(8)));
typedef __bf16 bf16x4 __attribute__((ext_vector_type(4)));
typedef float f32x4 __attribute__((ext_vector_type(4)));
typedef unsigned int u32;
typedef u32 u32x2 __attribute__((ext_vector_type(2)));

#define DM 1024
#define SEQL 2048
#define NTOK 4096
#define QKVN 3072

__device__ __forceinline__ void gload_lds16(const bf16_t* g, bf16_t* l){
  __builtin_amdgcn_global_load_lds((const __attribute__((address_space(1))) void*)g,
                                   (__attribute__((address_space(3))) void*)l, 16, 0, 0);
}
__device__ __forceinline__ u32 ldsoff(const void* p){
  return (u32)(size_t)(__attribute__((address_space(3))) const void*)p;
}
__device__ __forceinline__ u32x2 tr64(u32 byte_off){
  u32x2 d;
  asm volatile("ds_read_b64_tr_b16 %0, %1" : "=v"(d) : "v"(byte_off));
  return d;
}
__device__ __forceinline__ u32 pack2(float a, float b){
  union{ __bf16 h[2]; u32 w; } z;
  z.h[0]=(__bf16)a; z.h[1]=(__bf16)b; return z.w;
}

// ---------------- f32 -> bf16 convert (weights) ----------------
__global__ __launch_bounds__(256) void cvt_kernel(const float* __restrict__ src,
    bf16_t* __restrict__ dst, int n)
{
  const int i = (blockIdx.x*256 + threadIdx.x)*4;
  if (i < n){
    const float4 v = *(const float4*)(src + i);
    bf16x4 o; o[0]=(__bf16)v.x; o[1]=(__bf16)v.y; o[2]=(__bf16)v.z; o[3]=(__bf16)v.w;
    *(bf16x4*)(dst + i) = o;
  }
}

// ---------------- LayerNorm ----------------
__global__ __launch_bounds__(256) void ln_kernel(const float* __restrict__ in,
    const float* __restrict__ g, const float* __restrict__ bta,
    bf16_t* __restrict__ outp)
{
  const int row = blockIdx.x;
  const int t = threadIdx.x;
  const float4 v = *(const float4*)(in + (size_t)row*DM + t*4);
  float s  = v.x+v.y+v.z+v.w;
  float sq = v.x*v.x+v.y*v.y+v.z*v.z+v.w*v.w;
  #pragma unroll
  for (int m=1;m<64;m<<=1){ s += __shfl_xor(s,m); sq += __shfl_xor(sq,m); }
  __shared__ float red[8];
  const int w = t>>6;
  if ((t&63)==0){ red[w]=s; red[4+w]=sq; }
  __syncthreads();
  s  = red[0]+red[1]+red[2]+red[3];
  sq = red[4]+red[5]+red[6]+red[7];
  const float mean = s*(1.f/DM);
  const float var  = sq*(1.f/DM) - mean*mean;
  const float rstd = rsqrtf(var + 1e-5f);
  const float4 gg = *(const float4*)(g + t*4);
  const float4 bb = *(const float4*)(bta + t*4);
  bf16x4 o;
  o[0]=(__bf16)((v.x-mean)*rstd*gg.x+bb.x);
  o[1]=(__bf16)((v.y-mean)*rstd*gg.y+bb.y);
  o[2]=(__bf16)((v.z-mean)*rstd*gg.z+bb.z);
  o[3]=(__bf16)((v.w-mean)*rstd*gg.w+bb.w);
  *(bf16x4*)(outp + (size_t)row*DM + t*4) = o;
}

// ---------------- 256x256 phase-split GEMM, triple-buffered counted pipeline ------------
// XCD-pinned mapping: XCD k owns 2 bm-panels (A resident in L2), sweeps all bn.
template<int EPI>
__global__ __launch_bounds__(512, 2) void gemm256(
    const bf16_t* __restrict__ A, const bf16_t* __restrict__ Bw,
    void* __restrict__ Cout, int N, int K)
{
  constexpr int BK = 32;
  __shared__ __align__(16) char ldsb[3*32768];   // 96 KB
  const int tid = threadIdx.x, lane = tid&63, wid = tid>>6;
  const int q16 = lane&15, g = lane>>4;
  const int wm = wid>>2, wn = wid&3;

  // XCD-pinned tile mapping (gridDim.x == 16, nwg % 8 == 0)
  const int flat = blockIdx.y*gridDim.x + blockIdx.x;
  const int xcd = flat&7, j = flat>>3;
  const int NY = gridDim.y;
  const int jdiv = j/NY, jmod = j - jdiv*NY;
  const int bm = (xcd*2 + jdiv)*256, bn = jmod*256;

  // staging source mapping: linear LDS dest L=tid*16 holds logical element L^swz
  int mloc, kloc;
  {
    const u32 L = tid*16;
    const u32 logical = L ^ (((L>>9)&1)<<5);
    mloc = (int)((logical>>10)*16 + ((logical&1023)>>6));
    kloc = (int)((logical&63)>>1);
  }
  const bf16_t* asrc[2]; const bf16_t* bsrc[2];
  #pragma unroll
  for (int ht=0; ht<2; ht++){
    asrc[ht] = A  + (size_t)(bm + ht*128 + mloc)*K + kloc;
    bsrc[ht] = Bw + (size_t)(bn + ht*128 + mloc)*K + kloc;
  }
  const u32 laneOff = ((u32)(q16*64 + g*16)) ^ ((u32)(q16&8)<<2);

  f32x4 acc[8][4] = {};

  auto stageA = [&](int buf, int ht, int k0){
    gload_lds16(asrc[ht] + k0, (bf16_t*)(ldsb + buf*32768 + ht*8192 + tid*16));
  };
  auto stageB = [&](int buf, int ht, int k0){
    gload_lds16(bsrc[ht] + k0, (bf16_t*)(ldsb + buf*32768 + 16384 + ht*8192 + tid*16));
  };

  stageA(0,0,0); stageA(0,1,0); stageB(0,0,0); stageB(0,1,0);
  stageA(1,0,BK); stageA(1,1,BK); stageB(1,0,BK); stageB(1,1,BK);
  asm volatile("s_waitcnt vmcnt(4)" ::: "memory");
  __builtin_amdgcn_s_barrier();

  const int NT = K/BK;
  int bcur = 0;
  for (int kt=0; kt<NT; kt++){
    const int bstg = (bcur >= 1) ? bcur-1 : bcur+2;     // (bcur+2)%3
    const char* Ab = ldsb + bcur*32768 + wm*8192;
    const char* Bb = ldsb + bcur*32768 + 16384 + (wn>>1)*8192;
    const bool sOK = (kt+2 < NT);
    const int k0s = (kt+2)*BK;
    bf16x8 bv[4];
    #pragma unroll
    for (int p=0; p<2; p++){
      bf16x8 av[4];
      #pragma unroll
      for (int jx=0;jx<4;jx++)
        av[jx] = *(const bf16x8*)(Ab + ((p*4+jx)<<10) + laneOff);
      if (p==0){
        #pragma unroll
        for (int jx=0;jx<4;jx++)
          bv[jx] = *(const bf16x8*)(Bb + ((((wn&1)*4)+jx)<<10) + laneOff);
      }
      if (sOK){
        if (p==0){ stageA(bstg,0,k0s); stageA(bstg,1,k0s); }
        else     { stageB(bstg,0,k0s); stageB(bstg,1,k0s); }
      }
      asm volatile("s_barrier" ::: "memory");
      __builtin_amdgcn_s_setprio(1);
      #pragma unroll
      for (int jx=0;jx<4;jx++)
        #pragma unroll
        for (int j2=0;j2<4;j2++)
          acc[p*4+jx][j2] = __builtin_amdgcn_mfma_f32_16x16x32_bf16(av[jx], bv[j2], acc[p*4+jx][j2], 0,0,0);
      __builtin_amdgcn_s_setprio(0);
      if (p==1){
        if (sOK) asm volatile("s_waitcnt vmcnt(4)" ::: "memory");
        else     asm volatile("s_waitcnt vmcnt(0)" ::: "memory");
      }
      asm volatile("s_barrier" ::: "memory");
    }
    bcur = (bcur==2)?0:bcur+1;
  }

  #pragma unroll
  for (int fm=0; fm<8; fm++)
    #pragma unroll
    for (int fn=0; fn<4; fn++)
      #pragma unroll
      for (int i=0; i<4; i++){
        const int r = bm + wm*128 + fm*16 + g*4 + i;
        const int c = bn + wn*64 + fn*16 + q16;
        const size_t idx = (size_t)r*N + c;
        const float vv = acc[fm][fn][i];
        if constexpr (EPI==0){
          ((bf16_t*)Cout)[idx] = (__bf16)vv;
        } else {
          const float ge = 0.5f*vv*(1.0f + erff(vv*0.70710678118654752f));
          ((bf16_t*)Cout)[idx] = (__bf16)ge;
        }
      }
}

// ---------------- 128x128 phase-split GEMM (N=1024 outputs: WO, FF2) --------------------
// Same triple-buffered counted-vmcnt pipeline as gemm256, scaled down.
// 512 thr = 8 waves (2m x 4n), per-wave 64x32. LDS 3 x (A 8K + B 8K) = 48 KB.
// 2 loads/thread/tile -> vmcnt(2) mid-loop. EPI==1: fp32 store of X + C.
__global__ __launch_bounds__(512, 2) void gemm128(
    const bf16_t* __restrict__ A, const bf16_t* __restrict__ Bw,
    float* __restrict__ Cout, const float* __restrict__ X,
    int N, int K)
{
  constexpr int BK = 32;
  __shared__ __align__(16) char ldsb[3*16384];   // 48 KB
  const int tid = threadIdx.x, lane = tid&63, wid = tid>>6;
  const int q16 = lane&15, g = lane>>4;
  const int wm = wid>>2, wn = wid&3;

  // XCD-pinned: XCD k owns 4 bm-panels (A resident), sweeps 8 bn panels.
  const int flat = blockIdx.y*gridDim.x + blockIdx.x;   // grid 32x8 = 256
  const int xcd = flat&7, j = flat>>3;                  // j 0..31
  const int bm = ((xcd<<2) + (j>>3))*128, bn = (j&7)*128;

  int mloc, kloc;
  {
    const u32 L = tid*16;
    const u32 logical = L ^ (((L>>9)&1)<<5);
    mloc = (int)((logical>>10)*16 + ((logical&1023)>>6));
    kloc = (int)((logical&63)>>1);
  }
  const bf16_t* asrc = A  + (size_t)(bm + mloc)*K + kloc;
  const bf16_t* bsrc = Bw + (size_t)(bn + mloc)*K + kloc;
  const u32 laneOff = ((u32)(q16*64 + g*16)) ^ ((u32)(q16&8)<<2);

  f32x4 acc[4][2] = {};

  auto stageA = [&](int buf, int k0){
    gload_lds16(asrc + k0, (bf16_t*)(ldsb + buf*16384 + tid*16));
  };
  auto stageB = [&](int buf, int k0){
    gload_lds16(bsrc + k0, (bf16_t*)(ldsb + buf*16384 + 8192 + tid*16));
  };

  stageA(0,0); stageB(0,0);
  stageA(1,BK); stageB(1,BK);
  asm volatile("s_waitcnt vmcnt(2)" ::: "memory");
  __builtin_amdgcn_s_barrier();

  const int NT = K/BK;
  int bcur = 0;
  for (int kt=0; kt<NT; kt++){
    const int bstg = (bcur >= 1) ? bcur-1 : bcur+2;     // (bcur+2)%3
    const char* Ab = ldsb + bcur*16384 + wm*4096;
    const char* Bb = ldsb + bcur*16384 + 8192 + wn*2048;
    const bool sOK = (kt+2 < NT);
    const int k0s = (kt+2)*BK;
    bf16x8 bv[2];
    #pragma unroll
    for (int p=0; p<2; p++){
      bf16x8 av[2];
      #pragma unroll
      for (int jx=0;jx<2;jx++)
        av[jx] = *(const bf16x8*)(Ab + ((p*2+jx)<<10) + laneOff);
      if (p==0){
        #pragma unroll
        for (int jx=0;jx<2;jx++)
          bv[jx] = *(const bf16x8*)(Bb + (jx<<10) + laneOff);
      }
      if (sOK){
        if (p==0) stageA(bstg,k0s);
        else      stageB(bstg,k0s);
      }
      asm volatile("s_barrier" ::: "memory");
      __builtin_amdgcn_s_setprio(1);
      #pragma unroll
      for (int jx=0;jx<2;jx++)
        #pragma unroll
        for (int j2=0;j2<2;j2++)
          acc[p*2+jx][j2] = __builtin_amdgcn_mfma_f32_16x16x32_bf16(av[jx], bv[j2], acc[p*2+jx][j2], 0,0,0);
      __builtin_amdgcn_s_setprio(0);
      if (p==1){
        if (sOK) asm volatile("s_waitcnt vmcnt(2)" ::: "memory");
        else     asm volatile("s_waitcnt vmcnt(0)" ::: "memory");
      }
      asm volatile("s_barrier" ::: "memory");
    }
    bcur = (bcur==2)?0:bcur+1;
  }

  #pragma unroll
  for (int fm=0; fm<4; fm++)
    #pragma unroll
    for (int fn=0; fn<2; fn++)
      #pragma unroll
      for (int i=0; i<4; i++){
        const int r = bm + wm*64 + fm*16 + g*4 + i;
        const int c = bn + wn*32 + fn*16 + q16;
        const size_t idx = (size_t)r*N + c;
        Cout[idx] = X[idx] + acc[fm][fn][i];
      }
}

// ---------------- Flash attention v3: swapped QK^T + in-register softmax ----------------
__global__ __launch_bounds__(512, 4) void attn_kernel(
    const bf16_t* __restrict__ QKV, bf16_t* __restrict__ Ctx)
{
  __shared__ __align__(16) bf16_t Ks[2][64*64];
  __shared__ __align__(16) bf16_t Vs[2][16*4*72];
  const int tid = threadIdx.x, lane = tid&63, w = tid>>6;
  const int g = lane>>4, q16 = lane&15;
  const int bh = blockIdx.y, b = bh>>4, h = bh&15;
  const int qr0 = blockIdx.x*128 + w*16;
  const size_t tok0 = (size_t)b*SEQL;
  const int ch0 = h*64;

  bf16x8 aq[2];
  #pragma unroll
  for (int ks=0; ks<2; ks++){
    bf16x8 t = *(const bf16x8*)(QKV + (tok0+qr0+q16)*QKVN + ch0 + ks*32 + g*8);
    #pragma unroll
    for (int jx=0;jx<8;jx++) t[jx] = (__bf16)((float)t[jx]*0.125f);
    aq[ks] = t;
  }

  const int srow = tid>>3, sc8 = (tid&7)*8;
  const bf16_t* kptr = QKV + (tok0+srow)*QKVN + 1024 + ch0 + sc8;
  const bf16_t* vptr = kptr + 1024;
  const int kwoff = srow*64 + (sc8 ^ ((srow&7)<<3));
  const int vwoff = ((srow>>2)*4 + (sc8>>4))*72 + (srow&3)*16 + (sc8&15);

  float mrun = -1e30f, lrun = 0.f;
  f32x4 o[4] = {};

  bf16x8 kreg = *(const bf16x8*)kptr;
  bf16x8 vreg = *(const bf16x8*)vptr;
  *(bf16x8*)&Ks[0][kwoff] = kreg;
  *(bf16x8*)&Vs[0][vwoff] = vreg;
  kreg = *(const bf16x8*)(kptr + (size_t)64*QKVN);
  vreg = *(const bf16x8*)(vptr + (size_t)64*QKVN);

  const int NT = SEQL/64;
  for (int t=0; t<NT; t++){
    __syncthreads();
    if (t+1 < NT){
      *(bf16x8*)&Ks[(t+1)&1][kwoff] = kreg;
      *(bf16x8*)&Vs[(t+1)&1][vwoff] = vreg;
      if (t+2 < NT){
        kreg = *(const bf16x8*)(kptr + (size_t)(t+2)*64*QKVN);
        vreg = *(const bf16x8*)(vptr + (size_t)(t+2)*64*QKVN);
      }
    }
    const bf16_t* ksb = Ks[t&1];
    const u32 vs0 = ldsoff(&Vs[t&1][0]);

    f32x4 s[4] = {};
    #pragma unroll
    for (int ks=0; ks<2; ks++){
      #pragma unroll
      for (int fn=0; fn<4; fn++){
        const int r = fn*16 + q16;
        const int ce = ks*32 + g*8;
        bf16x8 bk = *(const bf16x8*)&ksb[r*64 + (ce ^ ((r&7)<<3))];
        s[fn] = __builtin_amdgcn_mfma_f32_16x16x32_bf16(bk, aq[ks], s[fn], 0, 0, 0);
      }
    }

    float m0 = fmaxf(fmaxf(s[0][0],s[0][1]), fmaxf(s[0][2],s[0][3]));
    float m1 = fmaxf(fmaxf(s[1][0],s[1][1]), fmaxf(s[1][2],s[1][3]));
    float m2 = fmaxf(fmaxf(s[2][0],s[2][1]), fmaxf(s[2][2],s[2][3]));
    float m3 = fmaxf(fmaxf(s[3][0],s[3][1]), fmaxf(s[3][2],s[3][3]));
    float mx = fmaxf(fmaxf(m0,m1), fmaxf(m2,m3));
    mx = fmaxf(mx, __shfl_xor(mx,16));
    mx = fmaxf(mx, __shfl_xor(mx,32));

    if (!__all(mx <= mrun + 8.0f)){
      const float mnew = fmaxf(mrun, mx);
      const float alpha = __expf(mrun - mnew);
      #pragma unroll
      for (int i=0;i<4;i++){
        const float ai = __shfl(alpha, g*4+i);
        o[0][i]*=ai; o[1][i]*=ai; o[2][i]*=ai; o[3][i]*=ai;
      }
      lrun *= alpha;
      mrun = mnew;
    }

    float rs = 0.f;
    u32 u[4][2];
    #pragma unroll
    for (int fn=0; fn<4; fn++){
      const float e0=__expf(s[fn][0]-mrun), e1=__expf(s[fn][1]-mrun);
      const float e2=__expf(s[fn][2]-mrun), e3=__expf(s[fn][3]-mrun);
      rs += (e0+e1)+(e2+e3);
      u[fn][0] = pack2(e0,e1);
      u[fn][1] = pack2(e2,e3);
    }
    rs += __shfl_xor(rs,16);
    rs += __shfl_xor(rs,32);
    lrun += rs;

    #pragma unroll
    for (int ks=0; ks<2; ks++){
      u32x2 vlo[4], vhi[4];
      #pragma unroll
      for (int ne=0; ne<4; ne++){
        const u32 vb = vs0 + (u32)((((ks*8 + 2*g)*4 + ne)*72 + q16)*2);
        vlo[ne] = tr64(vb);
        vhi[ne] = tr64(vb + 576);
      }
      union { u32 wd[4]; bf16x8 v; } pa;
      #pragma unroll
      for (int jj=0; jj<4; jj++){
        const int src = q16 + ((((g&1)<<1) + (jj>>1))<<4);
        const u32 a0 = (u32)__shfl((int)u[2*ks  ][jj&1], src);
        const u32 a1 = (u32)__shfl((int)u[2*ks+1][jj&1], src);
        pa.wd[jj] = (g&2) ? a1 : a0;
      }
      asm volatile("s_waitcnt lgkmcnt(0)" ::: "memory");
      __builtin_amdgcn_sched_barrier(0);
      union { u32x2 u2[2]; bf16x8 v; } cc;
      #pragma unroll
      for (int ne=0; ne<4; ne++){
        cc.u2[0]=vlo[ne]; cc.u2[1]=vhi[ne];
        o[ne] = __builtin_amdgcn_mfma_f32_16x16x32_bf16(pa.v, cc.v, o[ne], 0, 0, 0);
      }
    }
  }

  const float rl = 1.0f/lrun;
  #pragma unroll
  for (int i=0; i<4; i++){
    const float ri = __shfl(rl, g*4+i);
    #pragma unroll
    for (int ne=0; ne<4; ne++){
      const int r = qr0 + g*4 + i;
      Ctx[(tok0+r)*DM + ch0 + ne*16 + q16] = (__bf16)(o[ne][i]*ri);
    }
  }
}

// ---------------- launcher ----------------
extern "C" void kernel_launch(void* const* d_in, const int* in_sizes, int n_in,
                              void* d_out, int out_size, void* d_ws, size_t ws_size,
                              hipStream_t stream)
{
  (void)in_sizes; (void)n_in; (void)out_size; (void)ws_size;
  const float* x  = (const float*)d_in[0];
  const float* wq = (const float*)d_in[1];
  const float* wk = (const float*)d_in[2];
  const float* wv = (const float*)d_in[3];
  const float* wo = (const float*)d_in[4];
  const float* w1 = (const float*)d_in[5];
  const float* w2 = (const float*)d_in[6];
  const float* g1 = (const float*)d_in[7];
  const float* b1 = (const float*)d_in[8];
  const float* g2 = (const float*)d_in[9];
  const float* b2 = (const float*)d_in[10];
  float* out = (float*)d_out;
  char* ws = (char*)d_ws;
  const size_t MB = 1024ull*1024ull;

  bf16_t* wqkv_b = (bf16_t*)(ws);            // 6 MB  [3072][1024]
  bf16_t* wo_b   = (bf16_t*)(ws + 6*MB);     // 2 MB
  bf16_t* w1_b   = (bf16_t*)(ws + 8*MB);     // 8 MB
  bf16_t* w2_b   = (bf16_t*)(ws + 16*MB);    // 8 MB
  bf16_t* h1     = (bf16_t*)(ws + 24*MB);    // 8 MB
  bf16_t* qkv    = (bf16_t*)(ws + 32*MB);    // 24 MB [4096][3072]
  bf16_t* ctx    = (bf16_t*)(ws + 56*MB);    // 8 MB
  float*  res2   = (float*)(ws + 64*MB);     // 16 MB
  bf16_t* h2     = h1;                       // alias: h1 dead after QKV GEMM
  bf16_t* ffm    = (bf16_t*)(ws + 32*MB);    // alias qkv+ctx (dead by then)

  cvt_kernel<<<1024, 256, 0, stream>>>(wq, wqkv_b,             1024*1024);
  cvt_kernel<<<1024, 256, 0, stream>>>(wk, wqkv_b + 1024*1024, 1024*1024);
  cvt_kernel<<<1024, 256, 0, stream>>>(wv, wqkv_b + 2048*1024, 1024*1024);
  cvt_kernel<<<1024, 256, 0, stream>>>(wo, wo_b, 1024*1024);
  cvt_kernel<<<4096, 256, 0, stream>>>(w1, w1_b, 4096*1024);
  cvt_kernel<<<4096, 256, 0, stream>>>(w2, w2_b, 4096*1024);

  ln_kernel<<<NTOK, 256, 0, stream>>>(x, g1, b1, h1);
  gemm256<0><<<dim3(16, 12), 512, 0, stream>>>(h1, wqkv_b, (void*)qkv, QKVN, 1024);
  attn_kernel<<<dim3(16, 32), 512, 0, stream>>>(qkv, ctx);
  gemm128<<<dim3(32, 8), 512, 0, stream>>>(ctx, wo_b, res2, x, 1024, 1024);
  ln_kernel<<<NTOK, 256, 0, stream>>>(res2, g2, b2, h2);
  gemm256<2><<<dim3(16, 16), 512, 0, stream>>>(h2, w1_b, (void*)ffm, 4096, 1024);
  gemm128<<<dim3(32, 8), 512, 0, stream>>>(ffm, w2_b, out, x, 1024, 4096);
}

// Round 7
// 257.319 us; speedup vs baseline: 1.6095x; 1.0143x over previous
//
#include <hip/hip_runtime.h>
#include <hip/hip_bf16.h>
#include <math.h>

typedef __bf16 bf16_t;
typedef __bf16 bf16x8 __attribute__((ext_vector_type(8)));
typedef __bf16 bf16x4 __attribute__((ext_vector_type(4)));
typedef float f32x4 __attribute__((ext_vector_type(4)));
typedef unsigned int u32;
typedef u32 u32x2 __attribute__((ext_vector_type(2)));

#define DM 1024
#define SEQL 2048
#define NTOK 4096
#define QKVN 3072

__device__ __forceinline__ void gload_lds16(const bf16_t* g, bf16_t* l){
  __builtin_amdgcn_global_load_lds((const __attribute__((address_space(1))) void*)g,
                                   (__attribute__((address_space(3))) void*)l, 16, 0, 0);
}
__device__ __forceinline__ u32 ldsoff(const void* p){
  return (u32)(size_t)(__attribute__((address_space(3))) const void*)p;
}
__device__ __forceinline__ u32x2 tr64(u32 byte_off){
  u32x2 d;
  asm volatile("ds_read_b64_tr_b16 %0, %1" : "=v"(d) : "v"(byte_off));
  return d;
}
__device__ __forceinline__ u32 pack2(float a, float b){
  union{ __bf16 h[2]; u32 w; } z;
  z.h[0]=(__bf16)a; z.h[1]=(__bf16)b; return z.w;
}

// ---------------- prep: all weight cvts (12M elems) + LN1, one launch ----------------
// blocks [0,12288): bf16 convert, segments of 1M elems:
//   0-2: wq/wk/wv -> wqkv_b ; 3: wo -> wo_b ; 4-7: w1 -> w1_b ; 8-11: w2 -> w2_b
// blocks [12288,16384): LayerNorm1 row = bid-12288
__global__ __launch_bounds__(256) void prep_kernel(
    const float* __restrict__ wq, const float* __restrict__ wk,
    const float* __restrict__ wv, const float* __restrict__ wo,
    const float* __restrict__ w1, const float* __restrict__ w2,
    const float* __restrict__ x,  const float* __restrict__ g1,
    const float* __restrict__ b1,
    bf16_t* __restrict__ wqkv_b, bf16_t* __restrict__ wo_b,
    bf16_t* __restrict__ w1_b,   bf16_t* __restrict__ w2_b,
    bf16_t* __restrict__ h1)
{
  __shared__ float red[8];
  const int bid = blockIdx.x;
  const int t = threadIdx.x;
  if (bid < 12288){
    const int flat = (bid*256 + t)*4;
    const int seg = flat >> 20;
    const int off1m = flat & 1048575;
    const float* src; bf16_t* dst;
    if (seg < 3){
      src = (seg==0 ? wq : (seg==1 ? wk : wv)) + off1m;
      dst = wqkv_b + flat;
    } else if (seg == 3){
      src = wo + off1m;  dst = wo_b + off1m;
    } else if (seg < 8){
      src = w1 + (flat - 4*1048576);  dst = w1_b + (flat - 4*1048576);
    } else {
      src = w2 + (flat - 8*1048576);  dst = w2_b + (flat - 8*1048576);
    }
    const float4 v = *(const float4*)src;
    bf16x4 o; o[0]=(__bf16)v.x; o[1]=(__bf16)v.y; o[2]=(__bf16)v.z; o[3]=(__bf16)v.w;
    *(bf16x4*)dst = o;
  } else {
    const int row = bid - 12288;
    const float4 v = *(const float4*)(x + (size_t)row*DM + t*4);
    float s  = v.x+v.y+v.z+v.w;
    float sq = v.x*v.x+v.y*v.y+v.z*v.z+v.w*v.w;
    #pragma unroll
    for (int m=1;m<64;m<<=1){ s += __shfl_xor(s,m); sq += __shfl_xor(sq,m); }
    const int w = t>>6;
    if ((t&63)==0){ red[w]=s; red[4+w]=sq; }
    __syncthreads();
    s  = red[0]+red[1]+red[2]+red[3];
    sq = red[4]+red[5]+red[6]+red[7];
    const float mean = s*(1.f/DM);
    const float var  = sq*(1.f/DM) - mean*mean;
    const float rstd = rsqrtf(var + 1e-5f);
    const float4 gg = *(const float4*)(g1 + t*4);
    const float4 bb = *(const float4*)(b1 + t*4);
    bf16x4 o;
    o[0]=(__bf16)((v.x-mean)*rstd*gg.x+bb.x);
    o[1]=(__bf16)((v.y-mean)*rstd*gg.y+bb.y);
    o[2]=(__bf16)((v.z-mean)*rstd*gg.z+bb.z);
    o[3]=(__bf16)((v.w-mean)*rstd*gg.w+bb.w);
    *(bf16x4*)(h1 + (size_t)row*DM + t*4) = o;
  }
}

// ---------------- LayerNorm (LN2) ----------------
__global__ __launch_bounds__(256) void ln_kernel(const float* __restrict__ in,
    const float* __restrict__ g, const float* __restrict__ bta,
    bf16_t* __restrict__ outp)
{
  const int row = blockIdx.x;
  const int t = threadIdx.x;
  const float4 v = *(const float4*)(in + (size_t)row*DM + t*4);
  float s  = v.x+v.y+v.z+v.w;
  float sq = v.x*v.x+v.y*v.y+v.z*v.z+v.w*v.w;
  #pragma unroll
  for (int m=1;m<64;m<<=1){ s += __shfl_xor(s,m); sq += __shfl_xor(sq,m); }
  __shared__ float red[8];
  const int w = t>>6;
  if ((t&63)==0){ red[w]=s; red[4+w]=sq; }
  __syncthreads();
  s  = red[0]+red[1]+red[2]+red[3];
  sq = red[4]+red[5]+red[6]+red[7];
  const float mean = s*(1.f/DM);
  const float var  = sq*(1.f/DM) - mean*mean;
  const float rstd = rsqrtf(var + 1e-5f);
  const float4 gg = *(const float4*)(g + t*4);
  const float4 bb = *(const float4*)(bta + t*4);
  bf16x4 o;
  o[0]=(__bf16)((v.x-mean)*rstd*gg.x+bb.x);
  o[1]=(__bf16)((v.y-mean)*rstd*gg.y+bb.y);
  o[2]=(__bf16)((v.z-mean)*rstd*gg.z+bb.z);
  o[3]=(__bf16)((v.w-mean)*rstd*gg.w+bb.w);
  *(bf16x4*)(outp + (size_t)row*DM + t*4) = o;
}

// ---------------- 256x256 phase-split GEMM, triple-buffered counted pipeline ------------
template<int EPI>
__global__ __launch_bounds__(512, 2) void gemm256(
    const bf16_t* __restrict__ A, const bf16_t* __restrict__ Bw,
    void* __restrict__ Cout, int N, int K)
{
  constexpr int BK = 32;
  __shared__ __align__(16) char ldsb[3*32768];   // 96 KB
  const int tid = threadIdx.x, lane = tid&63, wid = tid>>6;
  const int q16 = lane&15, g = lane>>4;
  const int wm = wid>>2, wn = wid&3;

  const int flat = blockIdx.y*gridDim.x + blockIdx.x;
  const int xcd = flat&7, j = flat>>3;
  const int NY = gridDim.y;
  const int jdiv = j/NY, jmod = j - jdiv*NY;
  const int bm = (xcd*2 + jdiv)*256, bn = jmod*256;

  int mloc, kloc;
  {
    const u32 L = tid*16;
    const u32 logical = L ^ (((L>>9)&1)<<5);
    mloc = (int)((logical>>10)*16 + ((logical&1023)>>6));
    kloc = (int)((logical&63)>>1);
  }
  const bf16_t* asrc[2]; const bf16_t* bsrc[2];
  #pragma unroll
  for (int ht=0; ht<2; ht++){
    asrc[ht] = A  + (size_t)(bm + ht*128 + mloc)*K + kloc;
    bsrc[ht] = Bw + (size_t)(bn + ht*128 + mloc)*K + kloc;
  }
  const u32 laneOff = ((u32)(q16*64 + g*16)) ^ ((u32)(q16&8)<<2);

  f32x4 acc[8][4] = {};

  auto stageA = [&](int buf, int ht, int k0){
    gload_lds16(asrc[ht] + k0, (bf16_t*)(ldsb + buf*32768 + ht*8192 + tid*16));
  };
  auto stageB = [&](int buf, int ht, int k0){
    gload_lds16(bsrc[ht] + k0, (bf16_t*)(ldsb + buf*32768 + 16384 + ht*8192 + tid*16));
  };

  stageA(0,0,0); stageA(0,1,0); stageB(0,0,0); stageB(0,1,0);
  stageA(1,0,BK); stageA(1,1,BK); stageB(1,0,BK); stageB(1,1,BK);
  asm volatile("s_waitcnt vmcnt(4)" ::: "memory");
  __builtin_amdgcn_s_barrier();

  const int NT = K/BK;
  int bcur = 0;
  for (int kt=0; kt<NT; kt++){
    const int bstg = (bcur >= 1) ? bcur-1 : bcur+2;
    const char* Ab = ldsb + bcur*32768 + wm*8192;
    const char* Bb = ldsb + bcur*32768 + 16384 + (wn>>1)*8192;
    const bool sOK = (kt+2 < NT);
    const int k0s = (kt+2)*BK;
    bf16x8 bv[4];
    #pragma unroll
    for (int p=0; p<2; p++){
      bf16x8 av[4];
      #pragma unroll
      for (int jx=0;jx<4;jx++)
        av[jx] = *(const bf16x8*)(Ab + ((p*4+jx)<<10) + laneOff);
      if (p==0){
        #pragma unroll
        for (int jx=0;jx<4;jx++)
          bv[jx] = *(const bf16x8*)(Bb + ((((wn&1)*4)+jx)<<10) + laneOff);
      }
      if (sOK){
        if (p==0){ stageA(bstg,0,k0s); stageA(bstg,1,k0s); }
        else     { stageB(bstg,0,k0s); stageB(bstg,1,k0s); }
      }
      asm volatile("s_barrier" ::: "memory");
      __builtin_amdgcn_s_setprio(1);
      #pragma unroll
      for (int jx=0;jx<4;jx++)
        #pragma unroll
        for (int j2=0;j2<4;j2++)
          acc[p*4+jx][j2] = __builtin_amdgcn_mfma_f32_16x16x32_bf16(av[jx], bv[j2], acc[p*4+jx][j2], 0,0,0);
      __builtin_amdgcn_s_setprio(0);
      if (p==1){
        if (sOK) asm volatile("s_waitcnt vmcnt(4)" ::: "memory");
        else     asm volatile("s_waitcnt vmcnt(0)" ::: "memory");
      }
      asm volatile("s_barrier" ::: "memory");
    }
    bcur = (bcur==2)?0:bcur+1;
  }

  #pragma unroll
  for (int fm=0; fm<8; fm++)
    #pragma unroll
    for (int fn=0; fn<4; fn++)
      #pragma unroll
      for (int i=0; i<4; i++){
        const int r = bm + wm*128 + fm*16 + g*4 + i;
        const int c = bn + wn*64 + fn*16 + q16;
        const size_t idx = (size_t)r*N + c;
        const float vv = acc[fm][fn][i];
        if constexpr (EPI==0){
          ((bf16_t*)Cout)[idx] = (__bf16)vv;
        } else {
          const float ge = 0.5f*vv*(1.0f + erff(vv*0.70710678118654752f));
          ((bf16_t*)Cout)[idx] = (__bf16)ge;
        }
      }
}

// ---------------- 128x128 phase-split GEMM (N=1024 outputs: WO, FF2) --------------------
__global__ __launch_bounds__(512, 2) void gemm128(
    const bf16_t* __restrict__ A, const bf16_t* __restrict__ Bw,
    float* __restrict__ Cout, const float* __restrict__ X,
    int N, int K)
{
  constexpr int BK = 32;
  __shared__ __align__(16) char ldsb[3*16384];   // 48 KB
  const int tid = threadIdx.x, lane = tid&63, wid = tid>>6;
  const int q16 = lane&15, g = lane>>4;
  const int wm = wid>>2, wn = wid&3;

  const int flat = blockIdx.y*gridDim.x + blockIdx.x;   // grid 32x8 = 256
  const int xcd = flat&7, j = flat>>3;
  const int bm = ((xcd<<2) + (j>>3))*128, bn = (j&7)*128;

  int mloc, kloc;
  {
    const u32 L = tid*16;
    const u32 logical = L ^ (((L>>9)&1)<<5);
    mloc = (int)((logical>>10)*16 + ((logical&1023)>>6));
    kloc = (int)((logical&63)>>1);
  }
  const bf16_t* asrc = A  + (size_t)(bm + mloc)*K + kloc;
  const bf16_t* bsrc = Bw + (size_t)(bn + mloc)*K + kloc;
  const u32 laneOff = ((u32)(q16*64 + g*16)) ^ ((u32)(q16&8)<<2);

  f32x4 acc[4][2] = {};

  auto stageA = [&](int buf, int k0){
    gload_lds16(asrc + k0, (bf16_t*)(ldsb + buf*16384 + tid*16));
  };
  auto stageB = [&](int buf, int k0){
    gload_lds16(bsrc + k0, (bf16_t*)(ldsb + buf*16384 + 8192 + tid*16));
  };

  stageA(0,0); stageB(0,0);
  stageA(1,BK); stageB(1,BK);
  asm volatile("s_waitcnt vmcnt(2)" ::: "memory");
  __builtin_amdgcn_s_barrier();

  const int NT = K/BK;
  int bcur = 0;
  for (int kt=0; kt<NT; kt++){
    const int bstg = (bcur >= 1) ? bcur-1 : bcur+2;
    const char* Ab = ldsb + bcur*16384 + wm*4096;
    const char* Bb = ldsb + bcur*16384 + 8192 + wn*2048;
    const bool sOK = (kt+2 < NT);
    const int k0s = (kt+2)*BK;
    bf16x8 bv[2];
    #pragma unroll
    for (int p=0; p<2; p++){
      bf16x8 av[2];
      #pragma unroll
      for (int jx=0;jx<2;jx++)
        av[jx] = *(const bf16x8*)(Ab + ((p*2+jx)<<10) + laneOff);
      if (p==0){
        #pragma unroll
        for (int jx=0;jx<2;jx++)
          bv[jx] = *(const bf16x8*)(Bb + (jx<<10) + laneOff);
      }
      if (sOK){
        if (p==0) stageA(bstg,k0s);
        else      stageB(bstg,k0s);
      }
      asm volatile("s_barrier" ::: "memory");
      __builtin_amdgcn_s_setprio(1);
      #pragma unroll
      for (int jx=0;jx<2;jx++)
        #pragma unroll
        for (int j2=0;j2<2;j2++)
          acc[p*2+jx][j2] = __builtin_amdgcn_mfma_f32_16x16x32_bf16(av[jx], bv[j2], acc[p*2+jx][j2], 0,0,0);
      __builtin_amdgcn_s_setprio(0);
      if (p==1){
        if (sOK) asm volatile("s_waitcnt vmcnt(2)" ::: "memory");
        else     asm volatile("s_waitcnt vmcnt(0)" ::: "memory");
      }
      asm volatile("s_barrier" ::: "memory");
    }
    bcur = (bcur==2)?0:bcur+1;
  }

  #pragma unroll
  for (int fm=0; fm<4; fm++)
    #pragma unroll
    for (int fn=0; fn<2; fn++)
      #pragma unroll
      for (int i=0; i<4; i++){
        const int r = bm + wm*64 + fm*16 + g*4 + i;
        const int c = bn + wn*32 + fn*16 + q16;
        const size_t idx = (size_t)r*N + c;
        Cout[idx] = X[idx] + acc[fm][fn][i];
      }
}

// ---------------- Flash attention v4: KVBLK=128, exp2-domain softmax ----------------
// 512 thr, 8 waves x 16 q-rows. Swapped QK^T; in-register softmax; P via shfl.
// Q pre-scaled by 0.125*log2(e) so P = exp2(s - m). Defer-max THR = 8*log2(e).
__global__ __launch_bounds__(512, 4) void attn_kernel(
    const bf16_t* __restrict__ QKV, bf16_t* __restrict__ Ctx)
{
  __shared__ __align__(16) bf16_t Ks[2][128*64];     // 32 KB
  __shared__ __align__(16) bf16_t Vs[2][32*4*72];    // 36 KB
  const int tid = threadIdx.x, lane = tid&63, w = tid>>6;
  const int g = lane>>4, q16 = lane&15;
  const int bh = blockIdx.y, b = bh>>4, h = bh&15;
  const int qr0 = blockIdx.x*128 + w*16;
  const size_t tok0 = (size_t)b*SEQL;
  const int ch0 = h*64;

  // Q fragments, pre-scaled by 0.125*log2(e)
  bf16x8 aq[2];
  #pragma unroll
  for (int ks=0; ks<2; ks++){
    bf16x8 t = *(const bf16x8*)(QKV + (tok0+qr0+q16)*QKVN + ch0 + ks*32 + g*8);
    #pragma unroll
    for (int jx=0;jx<8;jx++) t[jx] = (__bf16)((float)t[jx]*0.18033688f);
    aq[ks] = t;
  }

  // staging: 512 threads cover 64 rows x 8 chunks; two row-halves it=0,1
  const int srow = tid>>3, sc8 = (tid&7)*8;
  const bf16_t* kptr = QKV + (tok0+srow)*QKVN + 1024 + ch0 + sc8;
  const bf16_t* vptr = kptr + 1024;
  const int kwoff = srow*64 + (sc8 ^ ((srow&7)<<3));                       // +it*4096
  const int vwoff = ((srow>>2)*4 + (sc8>>4))*72 + (srow&3)*16 + (sc8&15);  // +it*4608

  float mrun = -1e30f, lrun = 0.f;
  f32x4 o[4] = {};

  bf16x8 kreg[2], vreg[2];
  #pragma unroll
  for (int it=0; it<2; it++){
    kreg[it] = *(const bf16x8*)(kptr + (size_t)it*64*QKVN);
    vreg[it] = *(const bf16x8*)(vptr + (size_t)it*64*QKVN);
  }
  #pragma unroll
  for (int it=0; it<2; it++){
    *(bf16x8*)&Ks[0][kwoff + it*4096] = kreg[it];
    *(bf16x8*)&Vs[0][vwoff + it*4608] = vreg[it];
  }
  #pragma unroll
  for (int it=0; it<2; it++){
    kreg[it] = *(const bf16x8*)(kptr + (size_t)(128 + it*64)*QKVN);
    vreg[it] = *(const bf16x8*)(vptr + (size_t)(128 + it*64)*QKVN);
  }

  const int NT = SEQL/128;   // 16
  for (int t=0; t<NT; t++){
    __syncthreads();
    if (t+1 < NT){
      #pragma unroll
      for (int it=0; it<2; it++){
        *(bf16x8*)&Ks[(t+1)&1][kwoff + it*4096] = kreg[it];
        *(bf16x8*)&Vs[(t+1)&1][vwoff + it*4608] = vreg[it];
      }
      if (t+2 < NT){
        #pragma unroll
        for (int it=0; it<2; it++){
          kreg[it] = *(const bf16x8*)(kptr + (size_t)((t+2)*128 + it*64)*QKVN);
          vreg[it] = *(const bf16x8*)(vptr + (size_t)((t+2)*128 + it*64)*QKVN);
        }
      }
    }
    const bf16_t* ksb = Ks[t&1];
    const u32 vs0 = ldsoff(&Vs[t&1][0]);

    // ---- S^T = K Q^T (log2-scaled) ----
    f32x4 s[8] = {};
    #pragma unroll
    for (int ks=0; ks<2; ks++){
      #pragma unroll
      for (int fn=0; fn<8; fn++){
        const int r = fn*16 + q16;
        const int ce = ks*32 + g*8;
        bf16x8 bk = *(const bf16x8*)&ksb[r*64 + (ce ^ ((r&7)<<3))];
        s[fn] = __builtin_amdgcn_mfma_f32_16x16x32_bf16(bk, aq[ks], s[fn], 0, 0, 0);
      }
    }

    // ---- in-register online softmax (exp2 domain) ----
    float mx = -1e30f;
    #pragma unroll
    for (int fn=0; fn<8; fn++)
      mx = fmaxf(mx, fmaxf(fmaxf(s[fn][0],s[fn][1]), fmaxf(s[fn][2],s[fn][3])));
    mx = fmaxf(mx, __shfl_xor(mx,16));
    mx = fmaxf(mx, __shfl_xor(mx,32));

    if (!__all(mx <= mrun + 11.54f)){      // defer-max, THR = 8*log2e
      const float mnew = fmaxf(mrun, mx);
      const float alpha = exp2f(mrun - mnew);
      #pragma unroll
      for (int i=0;i<4;i++){
        const float ai = __shfl(alpha, g*4+i);
        o[0][i]*=ai; o[1][i]*=ai; o[2][i]*=ai; o[3][i]*=ai;
      }
      lrun *= alpha;
      mrun = mnew;
    }

    float rs = 0.f;
    u32 u[8][2];
    #pragma unroll
    for (int fn=0; fn<8; fn++){
      const float e0=exp2f(s[fn][0]-mrun), e1=exp2f(s[fn][1]-mrun);
      const float e2=exp2f(s[fn][2]-mrun), e3=exp2f(s[fn][3]-mrun);
      rs += (e0+e1)+(e2+e3);
      u[fn][0] = pack2(e0,e1);
      u[fn][1] = pack2(e2,e3);
    }
    rs += __shfl_xor(rs,16);
    rs += __shfl_xor(rs,32);
    lrun += rs;

    // ---- O += P V ----
    #pragma unroll
    for (int ks=0; ks<4; ks++){
      u32x2 vlo[4], vhi[4];
      #pragma unroll
      for (int ne=0; ne<4; ne++){
        const u32 vb = vs0 + (u32)((((ks*8 + 2*g)*4 + ne)*72 + q16)*2);
        vlo[ne] = tr64(vb);
        vhi[ne] = tr64(vb + 576);
      }
      union { u32 wd[4]; bf16x8 v; } pa;
      #pragma unroll
      for (int jj=0; jj<4; jj++){
        const int src = q16 + ((((g&1)<<1) + (jj>>1))<<4);
        const u32 a0 = (u32)__shfl((int)u[2*ks  ][jj&1], src);
        const u32 a1 = (u32)__shfl((int)u[2*ks+1][jj&1], src);
        pa.wd[jj] = (g&2) ? a1 : a0;
      }
      asm volatile("s_waitcnt lgkmcnt(0)" ::: "memory");
      __builtin_amdgcn_sched_barrier(0);
      union { u32x2 u2[2]; bf16x8 v; } cc;
      #pragma unroll
      for (int ne=0; ne<4; ne++){
        cc.u2[0]=vlo[ne]; cc.u2[1]=vhi[ne];
        o[ne] = __builtin_amdgcn_mfma_f32_16x16x32_bf16(pa.v, cc.v, o[ne], 0, 0, 0);
      }
    }
  }

  const float rl = 1.0f/lrun;
  #pragma unroll
  for (int i=0; i<4; i++){
    const float ri = __shfl(rl, g*4+i);
    #pragma unroll
    for (int ne=0; ne<4; ne++){
      const int r = qr0 + g*4 + i;
      Ctx[(tok0+r)*DM + ch0 + ne*16 + q16] = (__bf16)(o[ne][i]*ri);
    }
  }
}

// ---------------- launcher ----------------
extern "C" void kernel_launch(void* const* d_in, const int* in_sizes, int n_in,
                              void* d_out, int out_size, void* d_ws, size_t ws_size,
                              hipStream_t stream)
{
  (void)in_sizes; (void)n_in; (void)out_size; (void)ws_size;
  const float* x  = (const float*)d_in[0];
  const float* wq = (const float*)d_in[1];
  const float* wk = (const float*)d_in[2];
  const float* wv = (const float*)d_in[3];
  const float* wo = (const float*)d_in[4];
  const float* w1 = (const float*)d_in[5];
  const float* w2 = (const float*)d_in[6];
  const float* g1 = (const float*)d_in[7];
  const float* b1 = (const float*)d_in[8];
  const float* g2 = (const float*)d_in[9];
  const float* b2 = (const float*)d_in[10];
  float* out = (float*)d_out;
  char* ws = (char*)d_ws;
  const size_t MB = 1024ull*1024ull;

  bf16_t* wqkv_b = (bf16_t*)(ws);            // 6 MB  [3072][1024]
  bf16_t* wo_b   = (bf16_t*)(ws + 6*MB);     // 2 MB
  bf16_t* w1_b   = (bf16_t*)(ws + 8*MB);     // 8 MB
  bf16_t* w2_b   = (bf16_t*)(ws + 16*MB);    // 8 MB
  bf16_t* h1     = (bf16_t*)(ws + 24*MB);    // 8 MB
  bf16_t* qkv    = (bf16_t*)(ws + 32*MB);    // 24 MB [4096][3072]
  bf16_t* ctx    = (bf16_t*)(ws + 56*MB);    // 8 MB
  float*  res2   = (float*)(ws + 64*MB);     // 16 MB
  bf16_t* h2     = h1;                       // alias: h1 dead after QKV GEMM
  bf16_t* ffm    = (bf16_t*)(ws + 32*MB);    // alias qkv+ctx (dead by then)

  prep_kernel<<<16384, 256, 0, stream>>>(wq, wk, wv, wo, w1, w2, x, g1, b1,
                                         wqkv_b, wo_b, w1_b, w2_b, h1);
  gemm256<0><<<dim3(16, 12), 512, 0, stream>>>(h1, wqkv_b, (void*)qkv, QKVN, 1024);
  attn_kernel<<<dim3(16, 32), 512, 0, stream>>>(qkv, ctx);
  gemm128<<<dim3(32, 8), 512, 0, stream>>>(ctx, wo_b, res2, x, 1024, 1024);
  ln_kernel<<<NTOK, 256, 0, stream>>>(res2, g2, b2, h2);
  gemm256<2><<<dim3(16, 16), 512, 0, stream>>>(h2, w1_b, (void*)ffm, 4096, 1024);
  gemm128<<<dim3(32, 8), 512, 0, stream>>>(ffm, w2_b, out, x, 1024, 4096);
}

// Round 8
// 247.231 us; speedup vs baseline: 1.6752x; 1.0408x over previous
//
#include <hip/hip_runtime.h>
#include <hip/hip_bf16.h>
#include <math.h>

typedef __bf16 bf16_t;
typedef __bf16 bf16x8 __attribute__((ext_vector_type(8)));
typedef __bf16 bf16x4 __attribute__((ext_vector_type(4)));
typedef float f32x4 __attribute__((ext_vector_type(4)));
typedef unsigned int u32;
typedef u32 u32x2 __attribute__((ext_vector_type(2)));

#define DM 1024
#define SEQL 2048
#define NTOK 4096
#define QKVN 3072

__device__ __forceinline__ void gload_lds16(const bf16_t* g, bf16_t* l){
  __builtin_amdgcn_global_load_lds((const __attribute__((address_space(1))) void*)g,
                                   (__attribute__((address_space(3))) void*)l, 16, 0, 0);
}
__device__ __forceinline__ u32 ldsoff(const void* p){
  return (u32)(size_t)(__attribute__((address_space(3))) const void*)p;
}
__device__ __forceinline__ u32x2 tr64(u32 byte_off){
  u32x2 d;
  asm volatile("ds_read_b64_tr_b16 %0, %1" : "=v"(d) : "v"(byte_off));
  return d;
}
__device__ __forceinline__ u32 pack2(float a, float b){
  union{ __bf16 h[2]; u32 w; } z;
  z.h[0]=(__bf16)a; z.h[1]=(__bf16)b; return z.w;
}

// ---------------- prep: all weight cvts (12M elems) + LN1, one launch ----------------
__global__ __launch_bounds__(256) void prep_kernel(
    const float* __restrict__ wq, const float* __restrict__ wk,
    const float* __restrict__ wv, const float* __restrict__ wo,
    const float* __restrict__ w1, const float* __restrict__ w2,
    const float* __restrict__ x,  const float* __restrict__ g1,
    const float* __restrict__ b1,
    bf16_t* __restrict__ wqkv_b, bf16_t* __restrict__ wo_b,
    bf16_t* __restrict__ w1_b,   bf16_t* __restrict__ w2_b,
    bf16_t* __restrict__ h1)
{
  __shared__ float red[8];
  const int bid = blockIdx.x;
  const int t = threadIdx.x;
  if (bid < 12288){
    const int flat = (bid*256 + t)*4;
    const int seg = flat >> 20;
    const int off1m = flat & 1048575;
    const float* src; bf16_t* dst;
    if (seg < 3){
      src = (seg==0 ? wq : (seg==1 ? wk : wv)) + off1m;
      dst = wqkv_b + flat;
    } else if (seg == 3){
      src = wo + off1m;  dst = wo_b + off1m;
    } else if (seg < 8){
      src = w1 + (flat - 4*1048576);  dst = w1_b + (flat - 4*1048576);
    } else {
      src = w2 + (flat - 8*1048576);  dst = w2_b + (flat - 8*1048576);
    }
    const float4 v = *(const float4*)src;
    bf16x4 o; o[0]=(__bf16)v.x; o[1]=(__bf16)v.y; o[2]=(__bf16)v.z; o[3]=(__bf16)v.w;
    *(bf16x4*)dst = o;
  } else {
    const int row = bid - 12288;
    const float4 v = *(const float4*)(x + (size_t)row*DM + t*4);
    float s  = v.x+v.y+v.z+v.w;
    float sq = v.x*v.x+v.y*v.y+v.z*v.z+v.w*v.w;
    #pragma unroll
    for (int m=1;m<64;m<<=1){ s += __shfl_xor(s,m); sq += __shfl_xor(sq,m); }
    const int w = t>>6;
    if ((t&63)==0){ red[w]=s; red[4+w]=sq; }
    __syncthreads();
    s  = red[0]+red[1]+red[2]+red[3];
    sq = red[4]+red[5]+red[6]+red[7];
    const float mean = s*(1.f/DM);
    const float var  = sq*(1.f/DM) - mean*mean;
    const float rstd = rsqrtf(var + 1e-5f);
    const float4 gg = *(const float4*)(g1 + t*4);
    const float4 bb = *(const float4*)(b1 + t*4);
    bf16x4 o;
    o[0]=(__bf16)((v.x-mean)*rstd*gg.x+bb.x);
    o[1]=(__bf16)((v.y-mean)*rstd*gg.y+bb.y);
    o[2]=(__bf16)((v.z-mean)*rstd*gg.z+bb.z);
    o[3]=(__bf16)((v.w-mean)*rstd*gg.w+bb.w);
    *(bf16x4*)(h1 + (size_t)row*DM + t*4) = o;
  }
}

// ---------------- LayerNorm (LN2) ----------------
__global__ __launch_bounds__(256) void ln_kernel(const float* __restrict__ in,
    const float* __restrict__ g, const float* __restrict__ bta,
    bf16_t* __restrict__ outp)
{
  const int row = blockIdx.x;
  const int t = threadIdx.x;
  const float4 v = *(const float4*)(in + (size_t)row*DM + t*4);
  float s  = v.x+v.y+v.z+v.w;
  float sq = v.x*v.x+v.y*v.y+v.z*v.z+v.w*v.w;
  #pragma unroll
  for (int m=1;m<64;m<<=1){ s += __shfl_xor(s,m); sq += __shfl_xor(sq,m); }
  __shared__ float red[8];
  const int w = t>>6;
  if ((t&63)==0){ red[w]=s; red[4+w]=sq; }
  __syncthreads();
  s  = red[0]+red[1]+red[2]+red[3];
  sq = red[4]+red[5]+red[6]+red[7];
  const float mean = s*(1.f/DM);
  const float var  = sq*(1.f/DM) - mean*mean;
  const float rstd = rsqrtf(var + 1e-5f);
  const float4 gg = *(const float4*)(g + t*4);
  const float4 bb = *(const float4*)(bta + t*4);
  bf16x4 o;
  o[0]=(__bf16)((v.x-mean)*rstd*gg.x+bb.x);
  o[1]=(__bf16)((v.y-mean)*rstd*gg.y+bb.y);
  o[2]=(__bf16)((v.z-mean)*rstd*gg.z+bb.z);
  o[3]=(__bf16)((v.w-mean)*rstd*gg.w+bb.w);
  *(bf16x4*)(outp + (size_t)row*DM + t*4) = o;
}

// ---------------- 256x256 8-phase GEMM (m201 template port) ----------------
// BM=BN=256, K-step 64, 2 steps/iter. LDS: 2 buf x {A,B} x 2 K-halves x 16KB = 128KB.
// Half-tile = one K-half (256 rows x 32 k). Stage->read gap >= 5 phases; vmcnt(4)
// checkpoints at ph4/ph8 (vmcnt(0) last iter). 8 waves (2m x 4n), per-wave 128x64.
template<int EPI>
__global__ __launch_bounds__(512, 2) void gemm8ph(
    const bf16_t* __restrict__ A, const bf16_t* __restrict__ Bw,
    void* __restrict__ Cout, int N, int K)
{
  __shared__ __align__(16) char ldsb[131072];
  const int tid = threadIdx.x, lane = tid&63, wid = tid>>6;
  const int q16 = lane&15, g = lane>>4;
  const int wm = wid>>2, wn = wid&3;

  // XCD-pinned tile map (nwg % 8 == 0; gridDim.y panels of bn)
  const int flat = blockIdx.y*gridDim.x + blockIdx.x;
  const int xcd = flat&7, jj = flat>>3;
  const int NY = gridDim.y;
  const int jdiv = jj/NY, jmod = jj - jdiv*NY;
  const int bm = (xcd*2 + jdiv)*256, bn = jmod*256;

  // staging decode: linear LDS dest L=tid*16 within an 8KB sub-half holds logical L^swz
  int mloc, kloc;
  {
    const u32 L = tid*16;
    const u32 logical = L ^ (((L>>9)&1)<<5);
    mloc = (int)(logical>>6);          // 0..127
    kloc = (int)((logical&63)>>1);     // 0..31
  }
  const bf16_t* asrc = A  + (size_t)(bm + mloc)*K + kloc;
  const bf16_t* bsrc = Bw + (size_t)(bn + mloc)*K + kloc;
  const u32 laneOff = ((u32)(q16*64 + g*16)) ^ ((u32)(q16&8)<<2);

  f32x4 acc[8][4] = {};
  bf16x8 bv[4];

  // one half-tile = 2 gload_lds (sub-halves of 128 rows)
  auto stage = [&](int buf, int kh, int isB, int s){
    const bf16_t* src = isB ? bsrc : asrc;
    #pragma unroll
    for (int h2=0; h2<2; h2++)
      gload_lds16(src + (size_t)(h2*128)*K + s*64 + kh*32,
                  (bf16_t*)(ldsb + buf*65536 + isB*32768 + kh*16384 + h2*8192 + tid*16));
  };

  // prologue: step0 all 4 half-tiles, step1 kh0 pair
  stage(0,0,0,0); stage(0,0,1,0); stage(0,1,0,0); stage(0,1,1,0);
  stage(1,0,0,1); stage(1,0,1,1);
  asm volatile("s_waitcnt vmcnt(4)" ::: "memory");
  __builtin_amdgcn_s_barrier();

  const int NSTEP = K>>6;
  const int NIT = NSTEP>>1;

#define PHASE(BUF,KH,MH,DOST,SBUF,SKH,SISB,SSTEP,CK) { \
    bf16x8 av[4]; \
    const char* Ab_ = ldsb + (BUF)*65536 + (KH)*16384 + wm*8192; \
    _Pragma("unroll") for (int jx=0;jx<4;jx++) \
      av[jx] = *(const bf16x8*)(Ab_ + (((MH)*4+jx)<<10) + laneOff); \
    if ((MH)==0){ \
      const char* Bb_ = ldsb + (BUF)*65536 + 32768 + (KH)*16384 + (wn>>1)*8192; \
      _Pragma("unroll") for (int jx=0;jx<4;jx++) \
        bv[jx] = *(const bf16x8*)(Bb_ + ((((wn&1)*4)+jx)<<10) + laneOff); \
    } \
    if (DOST) stage(SBUF,SKH,SISB,SSTEP); \
    asm volatile("s_barrier" ::: "memory"); \
    asm volatile("s_waitcnt lgkmcnt(0)" ::: "memory"); \
    __builtin_amdgcn_s_setprio(1); \
    _Pragma("unroll") for (int jx=0;jx<4;jx++) \
      _Pragma("unroll") for (int j2=0;j2<4;j2++) \
        acc[(MH)*4+jx][j2] = __builtin_amdgcn_mfma_f32_16x16x32_bf16(av[jx], bv[j2], acc[(MH)*4+jx][j2],0,0,0); \
    __builtin_amdgcn_s_setprio(0); \
    if (CK){ if (nl) { asm volatile("s_waitcnt vmcnt(4)" ::: "memory"); } \
             else    { asm volatile("s_waitcnt vmcnt(0)" ::: "memory"); } } \
    asm volatile("s_barrier" ::: "memory"); }

  for (int it=0; it<NIT; it++){
    const int s0 = 2*it, s1 = s0+1;
    const bool nl = (it+1 < NIT);
    PHASE(0,0,0, 1,  1,1,0, s1,   0)   // stage buf1.A-kh1 (s1)
    PHASE(0,0,1, 1,  1,1,1, s1,   0)   // stage buf1.B-kh1 (s1)
    PHASE(0,1,0, nl, 0,0,0, s0+2, 0)   // stage buf0.A-kh0 (s0+2)
    PHASE(0,1,1, nl, 0,0,1, s0+2, 1)   // stage buf0.B-kh0; ckpt
    PHASE(1,0,0, nl, 0,1,0, s0+2, 0)   // stage buf0.A-kh1
    PHASE(1,0,1, nl, 0,1,1, s0+2, 0)   // stage buf0.B-kh1
    PHASE(1,1,0, nl, 1,0,0, s1+2, 0)   // stage buf1.A-kh0 (s1+2)
    PHASE(1,1,1, nl, 1,0,1, s1+2, 1)   // stage buf1.B-kh0; ckpt
  }
#undef PHASE

  #pragma unroll
  for (int fm=0; fm<8; fm++)
    #pragma unroll
    for (int fn=0; fn<4; fn++)
      #pragma unroll
      for (int i=0; i<4; i++){
        const int r = bm + wm*128 + fm*16 + g*4 + i;
        const int c = bn + wn*64 + fn*16 + q16;
        const size_t idx = (size_t)r*N + c;
        const float vv = acc[fm][fn][i];
        if constexpr (EPI==0){
          ((bf16_t*)Cout)[idx] = (__bf16)vv;
        } else {
          const float ge = 0.5f*vv*(1.0f + erff(vv*0.70710678118654752f));
          ((bf16_t*)Cout)[idx] = (__bf16)ge;
        }
      }
}

// ---------------- 128x128 phase-split GEMM (N=1024 outputs: WO, FF2) --------------------
__global__ __launch_bounds__(512, 2) void gemm128(
    const bf16_t* __restrict__ A, const bf16_t* __restrict__ Bw,
    float* __restrict__ Cout, const float* __restrict__ X,
    int N, int K)
{
  constexpr int BK = 32;
  __shared__ __align__(16) char ldsb[3*16384];   // 48 KB
  const int tid = threadIdx.x, lane = tid&63, wid = tid>>6;
  const int q16 = lane&15, g = lane>>4;
  const int wm = wid>>2, wn = wid&3;

  const int flat = blockIdx.y*gridDim.x + blockIdx.x;   // grid 32x8 = 256
  const int xcd = flat&7, j = flat>>3;
  const int bm = ((xcd<<2) + (j>>3))*128, bn = (j&7)*128;

  int mloc, kloc;
  {
    const u32 L = tid*16;
    const u32 logical = L ^ (((L>>9)&1)<<5);
    mloc = (int)(logical>>6);
    kloc = (int)((logical&63)>>1);
  }
  const bf16_t* asrc = A  + (size_t)(bm + mloc)*K + kloc;
  const bf16_t* bsrc = Bw + (size_t)(bn + mloc)*K + kloc;
  const u32 laneOff = ((u32)(q16*64 + g*16)) ^ ((u32)(q16&8)<<2);

  f32x4 acc[4][2] = {};

  auto stageA = [&](int buf, int k0){
    gload_lds16(asrc + k0, (bf16_t*)(ldsb + buf*16384 + tid*16));
  };
  auto stageB = [&](int buf, int k0){
    gload_lds16(bsrc + k0, (bf16_t*)(ldsb + buf*16384 + 8192 + tid*16));
  };

  stageA(0,0); stageB(0,0);
  stageA(1,BK); stageB(1,BK);
  asm volatile("s_waitcnt vmcnt(2)" ::: "memory");
  __builtin_amdgcn_s_barrier();

  const int NT = K/BK;
  int bcur = 0;
  for (int kt=0; kt<NT; kt++){
    const int bstg = (bcur >= 1) ? bcur-1 : bcur+2;
    const char* Ab = ldsb + bcur*16384 + wm*4096;
    const char* Bb = ldsb + bcur*16384 + 8192 + wn*2048;
    const bool sOK = (kt+2 < NT);
    const int k0s = (kt+2)*BK;
    bf16x8 bv[2];
    #pragma unroll
    for (int p=0; p<2; p++){
      bf16x8 av[2];
      #pragma unroll
      for (int jx=0;jx<2;jx++)
        av[jx] = *(const bf16x8*)(Ab + ((p*2+jx)<<10) + laneOff);
      if (p==0){
        #pragma unroll
        for (int jx=0;jx<2;jx++)
          bv[jx] = *(const bf16x8*)(Bb + (jx<<10) + laneOff);
      }
      if (sOK){
        if (p==0) stageA(bstg,k0s);
        else      stageB(bstg,k0s);
      }
      asm volatile("s_barrier" ::: "memory");
      __builtin_amdgcn_s_setprio(1);
      #pragma unroll
      for (int jx=0;jx<2;jx++)
        #pragma unroll
        for (int j2=0;j2<2;j2++)
          acc[p*2+jx][j2] = __builtin_amdgcn_mfma_f32_16x16x32_bf16(av[jx], bv[j2], acc[p*2+jx][j2], 0,0,0);
      __builtin_amdgcn_s_setprio(0);
      if (p==1){
        if (sOK) asm volatile("s_waitcnt vmcnt(2)" ::: "memory");
        else     asm volatile("s_waitcnt vmcnt(0)" ::: "memory");
      }
      asm volatile("s_barrier" ::: "memory");
    }
    bcur = (bcur==2)?0:bcur+1;
  }

  #pragma unroll
  for (int fm=0; fm<4; fm++)
    #pragma unroll
    for (int fn=0; fn<2; fn++)
      #pragma unroll
      for (int i=0; i<4; i++){
        const int r = bm + wm*64 + fm*16 + g*4 + i;
        const int c = bn + wn*32 + fn*16 + q16;
        const size_t idx = (size_t)r*N + c;
        Cout[idx] = X[idx] + acc[fm][fn][i];
      }
}

// ---------------- Flash attention v3 (round-5 version): swapped QK^T, KVBLK=64 ----------
__global__ __launch_bounds__(512, 4) void attn_kernel(
    const bf16_t* __restrict__ QKV, bf16_t* __restrict__ Ctx)
{
  __shared__ __align__(16) bf16_t Ks[2][64*64];
  __shared__ __align__(16) bf16_t Vs[2][16*4*72];
  const int tid = threadIdx.x, lane = tid&63, w = tid>>6;
  const int g = lane>>4, q16 = lane&15;
  const int bh = blockIdx.y, b = bh>>4, h = bh&15;
  const int qr0 = blockIdx.x*128 + w*16;
  const size_t tok0 = (size_t)b*SEQL;
  const int ch0 = h*64;

  bf16x8 aq[2];
  #pragma unroll
  for (int ks=0; ks<2; ks++){
    bf16x8 t = *(const bf16x8*)(QKV + (tok0+qr0+q16)*QKVN + ch0 + ks*32 + g*8);
    #pragma unroll
    for (int jx=0;jx<8;jx++) t[jx] = (__bf16)((float)t[jx]*0.125f);
    aq[ks] = t;
  }

  const int srow = tid>>3, sc8 = (tid&7)*8;
  const bf16_t* kptr = QKV + (tok0+srow)*QKVN + 1024 + ch0 + sc8;
  const bf16_t* vptr = kptr + 1024;
  const int kwoff = srow*64 + (sc8 ^ ((srow&7)<<3));
  const int vwoff = ((srow>>2)*4 + (sc8>>4))*72 + (srow&3)*16 + (sc8&15);

  float mrun = -1e30f, lrun = 0.f;
  f32x4 o[4] = {};

  bf16x8 kreg = *(const bf16x8*)kptr;
  bf16x8 vreg = *(const bf16x8*)vptr;
  *(bf16x8*)&Ks[0][kwoff] = kreg;
  *(bf16x8*)&Vs[0][vwoff] = vreg;
  kreg = *(const bf16x8*)(kptr + (size_t)64*QKVN);
  vreg = *(const bf16x8*)(vptr + (size_t)64*QKVN);

  const int NT = SEQL/64;
  for (int t=0; t<NT; t++){
    __syncthreads();
    if (t+1 < NT){
      *(bf16x8*)&Ks[(t+1)&1][kwoff] = kreg;
      *(bf16x8*)&Vs[(t+1)&1][vwoff] = vreg;
      if (t+2 < NT){
        kreg = *(const bf16x8*)(kptr + (size_t)(t+2)*64*QKVN);
        vreg = *(const bf16x8*)(vptr + (size_t)(t+2)*64*QKVN);
      }
    }
    const bf16_t* ksb = Ks[t&1];
    const u32 vs0 = ldsoff(&Vs[t&1][0]);

    f32x4 s[4] = {};
    #pragma unroll
    for (int ks=0; ks<2; ks++){
      #pragma unroll
      for (int fn=0; fn<4; fn++){
        const int r = fn*16 + q16;
        const int ce = ks*32 + g*8;
        bf16x8 bk = *(const bf16x8*)&ksb[r*64 + (ce ^ ((r&7)<<3))];
        s[fn] = __builtin_amdgcn_mfma_f32_16x16x32_bf16(bk, aq[ks], s[fn], 0, 0, 0);
      }
    }

    float m0 = fmaxf(fmaxf(s[0][0],s[0][1]), fmaxf(s[0][2],s[0][3]));
    float m1 = fmaxf(fmaxf(s[1][0],s[1][1]), fmaxf(s[1][2],s[1][3]));
    float m2 = fmaxf(fmaxf(s[2][0],s[2][1]), fmaxf(s[2][2],s[2][3]));
    float m3 = fmaxf(fmaxf(s[3][0],s[3][1]), fmaxf(s[3][2],s[3][3]));
    float mx = fmaxf(fmaxf(m0,m1), fmaxf(m2,m3));
    mx = fmaxf(mx, __shfl_xor(mx,16));
    mx = fmaxf(mx, __shfl_xor(mx,32));

    if (!__all(mx <= mrun + 8.0f)){
      const float mnew = fmaxf(mrun, mx);
      const float alpha = __expf(mrun - mnew);
      #pragma unroll
      for (int i=0;i<4;i++){
        const float ai = __shfl(alpha, g*4+i);
        o[0][i]*=ai; o[1][i]*=ai; o[2][i]*=ai; o[3][i]*=ai;
      }
      lrun *= alpha;
      mrun = mnew;
    }

    float rs = 0.f;
    u32 u[4][2];
    #pragma unroll
    for (int fn=0; fn<4; fn++){
      const float e0=__expf(s[fn][0]-mrun), e1=__expf(s[fn][1]-mrun);
      const float e2=__expf(s[fn][2]-mrun), e3=__expf(s[fn][3]-mrun);
      rs += (e0+e1)+(e2+e3);
      u[fn][0] = pack2(e0,e1);
      u[fn][1] = pack2(e2,e3);
    }
    rs += __shfl_xor(rs,16);
    rs += __shfl_xor(rs,32);
    lrun += rs;

    #pragma unroll
    for (int ks=0; ks<2; ks++){
      u32x2 vlo[4], vhi[4];
      #pragma unroll
      for (int ne=0; ne<4; ne++){
        const u32 vb = vs0 + (u32)((((ks*8 + 2*g)*4 + ne)*72 + q16)*2);
        vlo[ne] = tr64(vb);
        vhi[ne] = tr64(vb + 576);
      }
      union { u32 wd[4]; bf16x8 v; } pa;
      #pragma unroll
      for (int jj=0; jj<4; jj++){
        const int src = q16 + ((((g&1)<<1) + (jj>>1))<<4);
        const u32 a0 = (u32)__shfl((int)u[2*ks  ][jj&1], src);
        const u32 a1 = (u32)__shfl((int)u[2*ks+1][jj&1], src);
        pa.wd[jj] = (g&2) ? a1 : a0;
      }
      asm volatile("s_waitcnt lgkmcnt(0)" ::: "memory");
      __builtin_amdgcn_sched_barrier(0);
      union { u32x2 u2[2]; bf16x8 v; } cc;
      #pragma unroll
      for (int ne=0; ne<4; ne++){
        cc.u2[0]=vlo[ne]; cc.u2[1]=vhi[ne];
        o[ne] = __builtin_amdgcn_mfma_f32_16x16x32_bf16(pa.v, cc.v, o[ne], 0, 0, 0);
      }
    }
  }

  const float rl = 1.0f/lrun;
  #pragma unroll
  for (int i=0; i<4; i++){
    const float ri = __shfl(rl, g*4+i);
    #pragma unroll
    for (int ne=0; ne<4; ne++){
      const int r = qr0 + g*4 + i;
      Ctx[(tok0+r)*DM + ch0 + ne*16 + q16] = (__bf16)(o[ne][i]*ri);
    }
  }
}

// ---------------- launcher ----------------
extern "C" void kernel_launch(void* const* d_in, const int* in_sizes, int n_in,
                              void* d_out, int out_size, void* d_ws, size_t ws_size,
                              hipStream_t stream)
{
  (void)in_sizes; (void)n_in; (void)out_size; (void)ws_size;
  const float* x  = (const float*)d_in[0];
  const float* wq = (const float*)d_in[1];
  const float* wk = (const float*)d_in[2];
  const float* wv = (const float*)d_in[3];
  const float* wo = (const float*)d_in[4];
  const float* w1 = (const float*)d_in[5];
  const float* w2 = (const float*)d_in[6];
  const float* g1 = (const float*)d_in[7];
  const float* b1 = (const float*)d_in[8];
  const float* g2 = (const float*)d_in[9];
  const float* b2 = (const float*)d_in[10];
  float* out = (float*)d_out;
  char* ws = (char*)d_ws;
  const size_t MB = 1024ull*1024ull;

  bf16_t* wqkv_b = (bf16_t*)(ws);            // 6 MB  [3072][1024]
  bf16_t* wo_b   = (bf16_t*)(ws + 6*MB);     // 2 MB
  bf16_t* w1_b   = (bf16_t*)(ws + 8*MB);     // 8 MB
  bf16_t* w2_b   = (bf16_t*)(ws + 16*MB);    // 8 MB
  bf16_t* h1     = (bf16_t*)(ws + 24*MB);    // 8 MB
  bf16_t* qkv    = (bf16_t*)(ws + 32*MB);    // 24 MB [4096][3072]
  bf16_t* ctx    = (bf16_t*)(ws + 56*MB);    // 8 MB
  float*  res2   = (float*)(ws + 64*MB);     // 16 MB
  bf16_t* h2     = h1;                       // alias: h1 dead after QKV GEMM
  bf16_t* ffm    = (bf16_t*)(ws + 32*MB);    // alias qkv+ctx (dead by then)

  prep_kernel<<<16384, 256, 0, stream>>>(wq, wk, wv, wo, w1, w2, x, g1, b1,
                                         wqkv_b, wo_b, w1_b, w2_b, h1);
  gemm8ph<0><<<dim3(16, 12), 512, 0, stream>>>(h1, wqkv_b, (void*)qkv, QKVN, 1024);
  attn_kernel<<<dim3(16, 32), 512, 0, stream>>>(qkv, ctx);
  gemm128<<<dim3(32, 8), 512, 0, stream>>>(ctx, wo_b, res2, x, 1024, 1024);
  ln_kernel<<<NTOK, 256, 0, stream>>>(res2, g2, b2, h2);
  gemm8ph<2><<<dim3(16, 16), 512, 0, stream>>>(h2, w1_b, (void*)ffm, 4096, 1024);
  gemm128<<<dim3(32, 8), 512, 0, stream>>>(ffm, w2_b, out, x, 1024, 4096);
}